// Round 10
// baseline (286.790 us; speedup 1.0000x reference)
//
#include <hip/hip_runtime.h>
#include <math.h>

// ---------------------------------------------------------------------------
// GuardNet: 2-layer attention-weighted GCN.
// R10: (a) hd1 back to fp32 (fp16 layer-1 table polluted fnh -> layer-2 sim
// threshold flips; absmax 0.094 was 4% from failing). hd2 stays fp16.
// (b) CSR: drop hist matrix + k_mscan; k_bscat reserves per-bucket ranges via
// global atomic cursors (init = bbase) and scatters from register-stashed
// edges. Within-bucket order nondeterministic (k_csr re-bins; sums order-free).
// ---------------------------------------------------------------------------

#define ATT_CAP 96      // per-node LDS sim stash; deg>CAP falls back to recompute
#define EPB     2048    // edges per bucket-sort block (= 8 per thread at TB=256)
#define RPB     128     // rows per bucket (bucket = row>>7)
#define NBUCK_MAX 512
#define CAPB    4096    // max edges per bucket in k_csr LDS (mean 2048, +45 sigma)

typedef _Float16 half4 __attribute__((ext_vector_type(4)));

// normalize rows: fn[i] = x[i] / max(||x[i]||,1e-12). one wave per node.
__global__ void k_normfn(const float* __restrict__ fea, float* __restrict__ fn, int n)
{
    int gid  = blockIdx.x * blockDim.x + threadIdx.x;
    int wid  = gid >> 6;
    int lane = threadIdx.x & 63;
    if (wid >= n) return;
    float v = fea[(size_t)wid * 64 + lane];
    float s = v * v;
#pragma unroll
    for (int off = 32; off > 0; off >>= 1) s += __shfl_xor(s, off);
    float inv = 1.0f / fmaxf(sqrtf(s), 1e-12f);
    fn[(size_t)wid * 64 + lane] = v * inv;
}

// ---- bucket histogram: LDS hist -> btot atomics ----------------------------
__global__ void k_bhist(const int* __restrict__ row, int* __restrict__ btot,
                        int E, int nbuck)
{
    __shared__ int lh[NBUCK_MAX];
    int b = blockIdx.x;
    int ebeg = b * EPB, eend = ebeg + EPB; if (eend > E) eend = E;
    for (int i = threadIdx.x; i < nbuck; i += blockDim.x) lh[i] = 0;
    __syncthreads();
    for (int e = ebeg + threadIdx.x; e < eend; e += blockDim.x)
        atomicAdd(&lh[row[e] >> 7], 1);
    __syncthreads();
    for (int i = threadIdx.x; i < nbuck; i += blockDim.x)
        if (lh[i]) atomicAdd(btot + i, lh[i]);
}

// single wave: exclusive scan btot -> bbase (and gcur copy); bbase[nbuck]=total
__global__ void k_bscan(const int* __restrict__ btot, int* __restrict__ bbase,
                        int* __restrict__ gcur, int nbuck)
{
    int lane = threadIdx.x;            // 64 threads
    int K = (nbuck + 63) / 64;
    int beg = lane * K;
    int s = 0;
    for (int i = 0; i < K; ++i) { int idx = beg + i; if (idx < nbuck) s += btot[idx]; }
    int incl = s;
#pragma unroll
    for (int off = 1; off < 64; off <<= 1) {
        int v = __shfl_up(incl, off);
        if (lane >= off) incl += v;
    }
    int run = incl - s;
    for (int i = 0; i < K; ++i) {
        int idx = beg + i;
        if (idx < nbuck) { bbase[idx] = run; gcur[idx] = run; run += btot[idx]; }
    }
    if (lane == 63) bbase[nbuck] = incl;
}

// scatter with per-block range reservation: LDS hist over register-stashed
// edges, one global atomicAdd per (block,bucket) reserves the range, then
// LDS-cursor scatter of packed (localrow<<16 | col) into ebuf.
__global__ void k_bscat(const int* __restrict__ row, const int* __restrict__ col,
                        int* __restrict__ gcur, int* __restrict__ ebuf, int E, int nbuck)
{
    __shared__ int lh[NBUCK_MAX];
    __shared__ int lbase[NBUCK_MAX];
    int b = blockIdx.x;
    int ebeg = b * EPB, eend = ebeg + EPB; if (eend > E) eend = E;
    int rr[8], cc[8];
    int ne = 0;
    for (int i = threadIdx.x; i < nbuck; i += blockDim.x) lh[i] = 0;
    __syncthreads();
    for (int e = ebeg + threadIdx.x; e < eend; e += blockDim.x) {
        int r = row[e], c = col[e];
        rr[ne] = r; cc[ne] = c; ++ne;
        atomicAdd(&lh[r >> 7], 1);
    }
    __syncthreads();
    for (int i = threadIdx.x; i < nbuck; i += blockDim.x) {
        int cnt = lh[i];
        if (cnt) lbase[i] = atomicAdd(gcur + i, cnt);
        lh[i] = 0;                       // reuse as local cursor
    }
    __syncthreads();
    for (int k = 0; k < ne; ++k) {
        int j = rr[k] >> 7;
        int pos = lbase[j] + atomicAdd(&lh[j], 1);
        ebuf[pos] = ((rr[k] & (RPB - 1)) << 16) | cc[k];
    }
}

// one block per bucket: LDS row-binning; coalesced col_s + rptr writes.
__global__ void k_csr(const int* __restrict__ ebuf, const int* __restrict__ bbase,
                      int* __restrict__ rptr, int* __restrict__ col_s, int N, int E)
{
    __shared__ int pk[CAPB];
    __shared__ int lcol[CAPB];
    __shared__ int lcnt[RPB], lexc[RPB], lcur[RPB];
    int j = blockIdx.x;
    int beg = bbase[j], end = bbase[j + 1];
    int m = end - beg; if (m > CAPB) m = CAPB;   // never hit (mean 2048, +45 sigma)
    int tid = threadIdx.x;
    for (int i = tid; i < m; i += blockDim.x) pk[i] = ebuf[beg + i];
    if (tid < RPB) lcnt[tid] = 0;
    __syncthreads();
    for (int i = tid; i < m; i += blockDim.x) atomicAdd(&lcnt[pk[i] >> 16], 1);
    __syncthreads();
    if (tid < 64) {                    // wave 0 scans 128 counts (2 per lane)
        int a = lcnt[2 * tid], b2 = lcnt[2 * tid + 1];
        int s = a + b2;
        int incl = s;
#pragma unroll
        for (int off = 1; off < 64; off <<= 1) {
            int v = __shfl_up(incl, off);
            if (tid >= off) incl += v;
        }
        int base = incl - s;
        lexc[2 * tid] = base;     lexc[2 * tid + 1] = base + a;
        lcur[2 * tid] = base;     lcur[2 * tid + 1] = base + a;
    }
    __syncthreads();
    for (int i = tid; i < m; i += blockDim.x) {
        int v = pk[i];
        int p = atomicAdd(&lcur[v >> 16], 1);
        lcol[p] = v & 0xFFFF;
    }
    __syncthreads();
    for (int i = tid; i < m; i += blockDim.x) col_s[beg + i] = lcol[i];
    if (tid < RPB) {
        int r = j * RPB + tid;
        if (r < N) rptr[r] = beg + lexc[tid];
    }
    if (j == 0 && tid == 0) rptr[N] = E;
}

// fused attention: per node (wave): pass1 = edge cosine sims (8 lanes/edge)
// stashed in LDS + wave-reduced row-sum; pass2 = w=exp(sim/rs), ballot-rank
// compaction into packed cw=(col, w), lend/dinv/selfc (= wself*di). No atomics.
__global__ void k_att(const float* __restrict__ fn,
                      const int* __restrict__ rptr, const int* __restrict__ col_s,
                      int2* __restrict__ cw, int* __restrict__ lend,
                      float* __restrict__ dinv, float* __restrict__ selfc, int n)
{
    __shared__ float ssim[4][ATT_CAP];
    __shared__ int   scol[4][ATT_CAP];
    int wib  = threadIdx.x >> 6;
    int wid  = blockIdx.x * 4 + wib;
    int lane = threadIdx.x & 63;
    if (wid >= n) return;
    int sub = lane & 7;
    int grp = lane >> 3;
    int beg = rptr[wid], end = rptr[wid + 1];
    int deg_all = end - beg;

    const float4* frp = (const float4*)(fn + (size_t)wid * 64);
    float4 a0 = frp[sub * 2], a1 = frp[sub * 2 + 1];

    // pass 1: sims + row-sum
    float rs_part = 0.0f;
    int ngrp = (deg_all + 7) >> 3;
    for (int g = 0; g < ngrp; ++g) {
        int li = g * 8 + grp;
        float s = 0.0f; int c = 0;
        bool valid = (li < deg_all);
        if (valid) {
            c = col_s[beg + li];
            const float4* fcp = (const float4*)(fn + (size_t)c * 64);
            float4 b0 = fcp[sub * 2], b1 = fcp[sub * 2 + 1];
            float p = a0.x * b0.x + a0.y * b0.y + a0.z * b0.z + a0.w * b0.w
                    + a1.x * b1.x + a1.y * b1.y + a1.z * b1.z + a1.w * b1.w;
            p += __shfl_xor(p, 1);
            p += __shfl_xor(p, 2);
            p += __shfl_xor(p, 4);
            s = (p < 0.1f) ? 0.0f : p;
        }
        if (sub == 0 && valid) {
            if (li < ATT_CAP) { ssim[wib][li] = s; scol[wib][li] = c; }
            if (s > 0.0f) rs_part += s;
        }
    }
#pragma unroll
    for (int off = 32; off > 0; off >>= 1) rs_part += __shfl_xor(rs_part, off);
    float denom = fmaxf(rs_part, 1e-12f);

    // pass 2: weights + live compaction (lane = edge index within 64-chunk)
    int   nlive = 0;
    float sw_lane = 0.0f;
    for (int base = 0; base < deg_all; base += 64) {
        int li = base + lane;
        bool valid = (li < deg_all);
        float s = 0.0f; int c = 0;
        if (valid) {
            if (li < ATT_CAP) { s = ssim[wib][li]; c = scol[wib][li]; }
            else {                           // astronomically rare: per-lane dot
                c = col_s[beg + li];
                const float* fr = fn + (size_t)wid * 64;
                const float* fc = fn + (size_t)c * 64;
                float p = 0.0f;
                for (int k = 0; k < 64; ++k) p += fr[k] * fc[k];
                s = (p < 0.1f) ? 0.0f : p;
            }
        }
        float w = (valid && s > 0.0f) ? expf(s / denom) : 0.0f;
        unsigned long long M = __ballot(w > 0.0f);
        int rank = __popcll(M & ((1ull << lane) - 1ull));
        if (w > 0.0f) {
            int2 pw; pw.x = c; pw.y = __float_as_int(w);
            cw[beg + nlive + rank] = pw;
            sw_lane += w;
        }
        nlive += __popcll(M);
    }
#pragma unroll
    for (int off = 32; off > 0; off >>= 1) sw_lane += __shfl_xor(sw_lane, off);

    if (lane == 0) {
        float wself = expf(1.0f / ((float)nlive + 1.0f));
        float D  = sw_lane + wself;
        float di = rsqrtf(fmaxf(D, 1e-12f));
        lend[wid]  = beg + nlive;
        dinv[wid]  = di;
        selfc[wid] = wself * di;   // self term applied to dinv-scaled table
    }
}

// dense GEMM out[N,F] = (fea[N,64] @ W[64,F]) * scale[r]; OutT element.
template <int F, typename InT, typename OutT>
__global__ void k_gemm(const InT* __restrict__ fea, const float* __restrict__ W,
                       const float* __restrict__ scale, OutT* __restrict__ out, int n)
{
    constexpr int R = 256 / F;
    __shared__ float sW[64 * F];
    __shared__ float sX[R * 64];
    int tid = threadIdx.x;
    for (int i = tid; i < 64 * F; i += 256) sW[i] = W[i];
    int base = blockIdx.x * R;
    for (int i = tid; i < R * 64; i += 256) {
        int rr = base + i / 64;
        sX[i] = (rr < n) ? (float)fea[(size_t)rr * 64 + (i & 63)] : 0.0f;
    }
    __syncthreads();
    int rl = tid / F, j = tid % F;
    if (rl >= R) return;
    int r = base + rl;
    if (r >= n) return;
    float acc = 0.0f;
#pragma unroll
    for (int k = 0; k < 64; ++k) acc = fmaf(sX[rl * 64 + k], sW[k * F + j], acc);
    out[(size_t)r * F + j] = (OutT)(acc * scale[r]);
}

// transposed live-edge aggregation, generic vec4 element (float4 / half4):
// 4 edges x 16 lanes; lane (eg,q) loads one vec4 of row c_eg at feature q*4.
// Returns per-lane (lane=feature) weighted sum via xor-reduce + transpose.
template <int F, typename Vec4>
__device__ inline float agg_core_t(const Vec4* __restrict__ hdv,
                                   const int2* __restrict__ cw,
                                   int beg, int lend_, int lane)
{
    int q  = lane & 15;
    int eg = lane >> 4;
    bool qact = (F == 64) ? true : (q < (F >> 2));
    float acc0 = 0.f, acc1 = 0.f, acc2 = 0.f, acc3 = 0.f;
    for (int base = beg; base < lend_; base += 64) {
        int idx = base + lane;
        int cv = 0; float wv = 0.0f;
        if (idx < lend_) { int2 pw = cw[idx]; cv = pw.x; wv = __int_as_float(pw.y); }
        int cnt = lend_ - base; if (cnt > 64) cnt = 64;
        for (int j = 0; j < cnt; j += 4) {
            int   c = __shfl(cv, j + eg);   // beyond-cnt lanes hold cv=0,wv=0
            float w = __shfl(wv, j + eg);
            if (qact) {
                Vec4 hv = hdv[(size_t)c * (F >> 2) + q];
                acc0 += w * (float)hv.x;
                acc1 += w * (float)hv.y;
                acc2 += w * (float)hv.z;
                acc3 += w * (float)hv.w;
            }
        }
    }
    acc0 += __shfl_xor(acc0, 16); acc0 += __shfl_xor(acc0, 32);
    acc1 += __shfl_xor(acc1, 16); acc1 += __shfl_xor(acc1, 32);
    acc2 += __shfl_xor(acc2, 16); acc2 += __shfl_xor(acc2, 32);
    acc3 += __shfl_xor(acc3, 16); acc3 += __shfl_xor(acc3, 32);
    int srcq = lane >> 2;
    float a0 = __shfl(acc0, srcq);
    float a1 = __shfl(acc1, srcq);
    float a2 = __shfl(acc2, srcq);
    float a3 = __shfl(acc3, srcq);
    int k = lane & 3;
    return (k == 0) ? a0 : (k == 1) ? a1 : (k == 2) ? a2 : a3;
}

// layer-1 aggregation over fp32 dinv-scaled table + relu; emits hrelu16 + fnh
__global__ void k_agg64(const float* __restrict__ hd, const int2* __restrict__ cw,
                        const float* __restrict__ dinv, const float* __restrict__ selfc,
                        const float* __restrict__ b, const int* __restrict__ row_ptr,
                        const int* __restrict__ lend,
                        _Float16* __restrict__ hrelu16, float* __restrict__ fnh, int n)
{
    int gid  = blockIdx.x * blockDim.x + threadIdx.x;
    int wid  = gid >> 6;
    int lane = threadIdx.x & 63;
    if (wid >= n) return;
    int beg = row_ptr[wid], le = lend[wid];
    float accf = agg_core_t<64>((const float4*)hd, cw, beg, le, lane);
    float hs  = hd[(size_t)wid * 64 + lane];  // = h*di
    float v = dinv[wid] * accf + selfc[wid] * hs + b[lane];
    v = fmaxf(v, 0.0f); // relu
    hrelu16[(size_t)wid * 64 + lane] = (_Float16)v;
    float s = v * v;
#pragma unroll
    for (int off = 32; off > 0; off >>= 1) s += __shfl_xor(s, off);
    float inv = 1.0f / fmaxf(sqrtf(s), 1e-12f);
    fnh[(size_t)wid * 64 + lane] = v * inv;
}

// layer-2 aggregation (F=40, fp16 table) + bias + log_softmax -> output.
__global__ void k_agg40_lsm(const _Float16* __restrict__ hd2, const int2* __restrict__ cw,
                            const float* __restrict__ dinv, const float* __restrict__ selfc,
                            const float* __restrict__ b, const int* __restrict__ row_ptr,
                            const int* __restrict__ lend,
                            float* __restrict__ out, int n)
{
    constexpr int F = 40;
    int gid  = blockIdx.x * blockDim.x + threadIdx.x;
    int wid  = gid >> 6;
    int lane = threadIdx.x & 63;
    if (wid >= n) return;
    int beg = row_ptr[wid], le = lend[wid];
    float accf = agg_core_t<F>((const half4*)hd2, cw, beg, le, lane);
    bool active = (lane < F);
    float v = 0.0f;
    if (active) {
        float hs = (float)hd2[(size_t)wid * F + lane];
        v = dinv[wid] * accf + selfc[wid] * hs + b[lane];
    }
    float m = active ? v : -__builtin_inff();
#pragma unroll
    for (int off = 32; off > 0; off >>= 1) m = fmaxf(m, __shfl_xor(m, off));
    float ex = active ? expf(v - m) : 0.0f;
    float s = ex;
#pragma unroll
    for (int off = 32; off > 0; off >>= 1) s += __shfl_xor(s, off);
    if (active) out[(size_t)wid * F + lane] = v - m - logf(s);
}

extern "C" void kernel_launch(void* const* d_in, const int* in_sizes, int n_in,
                              void* d_out, int out_size, void* d_ws, size_t ws_size,
                              hipStream_t stream)
{
    const float* x  = (const float*)d_in[0];
    const int*   ei = (const int*)d_in[1];
    const float* W1 = (const float*)d_in[2];
    const float* b1 = (const float*)d_in[3];
    const float* W2 = (const float*)d_in[4];
    const float* b2 = (const float*)d_in[5];
    float* out = (float*)d_out;

    const int N = in_sizes[0] / 64;   // 50000
    const int E = in_sizes[1] / 2;    // 800000
    const int* row = ei;
    const int* col = ei + E;

    const int nblkA = (E + EPB - 1) / EPB;       // edge blocks for bucket sort
    const int nbuck = (N + RPB - 1) / RPB;       // buckets (rows/128)

    char* p = (char*)d_ws;
    auto alloc = [&](size_t bytes) -> char* {
        char* r = p; p += (bytes + 255) & ~(size_t)255; return r;
    };
    float*     fn     = (float*)alloc((size_t)N * 64 * 4);     // normalized x
    float*     dinv   = (float*)alloc((size_t)N * 4);
    float*     selfc  = (float*)alloc((size_t)N * 4);
    float*     hd1    = (float*)alloc((size_t)N * 64 * 4);     // (x@W1)*di (fp32)
    _Float16*  hrelu  = (_Float16*)alloc((size_t)N * 64 * 2);  // relu out (fp16)
    _Float16*  hd2    = (_Float16*)alloc((size_t)N * 40 * 2);  // (hrelu@W2)*di2 (fp16)
    float*     fnh    = (float*)alloc((size_t)N * 64 * 4);     // normalized hrelu
    int*       rptr   = (int*)alloc((size_t)(N + 1) * 4);
    int*       lendv  = (int*)alloc((size_t)N * 4);
    int*       col_s  = (int*)alloc((size_t)E * 4);
    int2*      cw     = (int2*)alloc((size_t)E * 8);           // packed (col,w)
    int*       ebuf   = (int*)alloc((size_t)E * 4);            // bucketed packed edges
    int*       btot   = (int*)alloc((size_t)nbuck * 4);
    int*       bbase  = (int*)alloc((size_t)(nbuck + 1) * 4);
    int*       gcur   = (int*)alloc((size_t)nbuck * 4);

    const int TB = 256;
    int blk_nodeWave = (N * 64 + TB - 1) / TB;
    int blk_node4    = (N + 3) / 4;

    hipMemsetAsync(btot, 0, (size_t)nbuck * 4, stream);

    // ---- CSR build (bucket sort, atomic range reservation)
    k_bhist<<<nblkA, TB, 0, stream>>>(row, btot, E, nbuck);
    k_bscan<<<1, 64, 0, stream>>>(btot, bbase, gcur, nbuck);
    k_bscat<<<nblkA, TB, 0, stream>>>(row, col, gcur, ebuf, E, nbuck);
    k_csr<<<nbuck, TB, 0, stream>>>(ebuf, bbase, rptr, col_s, N, E);

    // ---- layer 1
    k_normfn<<<blk_nodeWave, TB, 0, stream>>>(x, fn, N);
    k_att<<<blk_node4, TB, 0, stream>>>(fn, rptr, col_s, cw, lendv, dinv, selfc, N);
    k_gemm<64, float, float><<<(N + 3) / 4, TB, 0, stream>>>(x, W1, dinv, hd1, N);
    k_agg64<<<blk_nodeWave, TB, 0, stream>>>(hd1, cw, dinv, selfc, b1,
                                             rptr, lendv, hrelu, fnh, N);

    // ---- layer 2
    k_att<<<blk_node4, TB, 0, stream>>>(fnh, rptr, col_s, cw, lendv, dinv, selfc, N);
    k_gemm<40, _Float16, _Float16><<<(N + 5) / 6, TB, 0, stream>>>(hrelu, W2, dinv, hd2, N);
    k_agg40_lsm<<<blk_nodeWave, TB, 0, stream>>>(hd2, cw, dinv, selfc, b2,
                                                 rptr, lendv, out, N);
}

// Round 11
// 273.847 us; speedup vs baseline: 1.0473x; 1.0473x over previous
//
#include <hip/hip_runtime.h>
#include <math.h>

// ---------------------------------------------------------------------------
// GuardNet: 2-layer attention-weighted GCN.
// R11: CSR chain compressed to 2 kernels: k_bscat scatters into slack-
// segmented ebuf (bucket j at j*CAPB) reserving ranges from zeroed gcur
// (post-hoc gcur == bucket counts, so no histogram pass); k_csr computes its
// own prefix sum of gcur (391 values/block, trivial) — no bbase kernel.
// Everything else = R10 (fp32 hd1, fp16 hd2, transposed agg, fused att).
// ---------------------------------------------------------------------------

#define ATT_CAP 96      // per-node LDS sim stash; deg>CAP falls back to recompute
#define EPB     2048    // edges per bucket-sort block (= 8 per thread at TB=256)
#define RPB     128     // rows per bucket (bucket = row>>7)
#define NBUCK_MAX 512
#define CAPB    4096    // slack per bucket (mean 2048, sigma~45 -> never hit)

typedef _Float16 half4 __attribute__((ext_vector_type(4)));

// normalize rows: fn[i] = x[i] / max(||x[i]||,1e-12). one wave per node.
__global__ void k_normfn(const float* __restrict__ fea, float* __restrict__ fn, int n)
{
    int gid  = blockIdx.x * blockDim.x + threadIdx.x;
    int wid  = gid >> 6;
    int lane = threadIdx.x & 63;
    if (wid >= n) return;
    float v = fea[(size_t)wid * 64 + lane];
    float s = v * v;
#pragma unroll
    for (int off = 32; off > 0; off >>= 1) s += __shfl_xor(s, off);
    float inv = 1.0f / fmaxf(sqrtf(s), 1e-12f);
    fn[(size_t)wid * 64 + lane] = v * inv;
}

// scatter into slack-segmented ebuf: LDS hist over register-stashed edges,
// one global atomicAdd per (block,bucket) reserves a range at j*CAPB + gcur[j],
// then LDS-cursor scatter of packed (localrow<<16 | col).
// After the grid completes, gcur[j] == bucket j's edge count.
__global__ void k_bscat(const int* __restrict__ row, const int* __restrict__ col,
                        int* __restrict__ gcur, int* __restrict__ ebuf, int E, int nbuck)
{
    __shared__ int lh[NBUCK_MAX];
    __shared__ int lbase[NBUCK_MAX];
    int b = blockIdx.x;
    int ebeg = b * EPB, eend = ebeg + EPB; if (eend > E) eend = E;
    int rr[8], cc[8];
    int ne = 0;
    for (int i = threadIdx.x; i < nbuck; i += blockDim.x) lh[i] = 0;
    __syncthreads();
    for (int e = ebeg + threadIdx.x; e < eend; e += blockDim.x) {
        int r = row[e], c = col[e];
        rr[ne] = r; cc[ne] = c; ++ne;
        atomicAdd(&lh[r >> 7], 1);
    }
    __syncthreads();
    for (int i = threadIdx.x; i < nbuck; i += blockDim.x) {
        int cnt = lh[i];
        if (cnt) lbase[i] = i * CAPB + atomicAdd(gcur + i, cnt);
        lh[i] = 0;                       // reuse as local cursor
    }
    __syncthreads();
    for (int k = 0; k < ne; ++k) {
        int j = rr[k] >> 7;
        int pos = lbase[j] + atomicAdd(&lh[j], 1);
        ebuf[pos] = ((rr[k] & (RPB - 1)) << 16) | cc[k];
    }
}

// one block per bucket: computes own exclusive prefix of gcur, LDS row-binning
// of its slack segment, coalesced col_s + rptr writes.
__global__ void k_csr(const int* __restrict__ ebuf, const int* __restrict__ gcur,
                      int* __restrict__ rptr, int* __restrict__ col_s,
                      int N, int E, int nbuck)
{
    __shared__ int pk[CAPB];
    __shared__ int lcol[CAPB];
    __shared__ int lcnt[RPB], lexc[RPB], lcur[RPB];
    __shared__ int spart[4];
    int j = blockIdx.x;
    int tid = threadIdx.x;
    int lane = tid & 63, wave = tid >> 6;

    // exclusive prefix: beg = sum(gcur[0..j))
    int part = 0;
    for (int i = tid; i < j; i += blockDim.x) part += gcur[i];
#pragma unroll
    for (int off = 32; off > 0; off >>= 1) part += __shfl_xor(part, off);
    if (lane == 0) spart[wave] = part;
    if (tid < RPB) lcnt[tid] = 0;
    __syncthreads();
    int beg = spart[0] + spart[1] + spart[2] + spart[3];
    int m = gcur[j]; if (m > CAPB) m = CAPB;     // never hit

    const int* seg = ebuf + (size_t)j * CAPB;
    for (int i = tid; i < m; i += blockDim.x) pk[i] = seg[i];
    __syncthreads();
    for (int i = tid; i < m; i += blockDim.x) atomicAdd(&lcnt[pk[i] >> 16], 1);
    __syncthreads();
    if (tid < 64) {                    // wave 0 scans 128 counts (2 per lane)
        int a = lcnt[2 * tid], b2 = lcnt[2 * tid + 1];
        int s = a + b2;
        int incl = s;
#pragma unroll
        for (int off = 1; off < 64; off <<= 1) {
            int v = __shfl_up(incl, off);
            if (tid >= off) incl += v;
        }
        int base = incl - s;
        lexc[2 * tid] = base;     lexc[2 * tid + 1] = base + a;
        lcur[2 * tid] = base;     lcur[2 * tid + 1] = base + a;
    }
    __syncthreads();
    for (int i = tid; i < m; i += blockDim.x) {
        int v = pk[i];
        int p = atomicAdd(&lcur[v >> 16], 1);
        lcol[p] = v & 0xFFFF;
    }
    __syncthreads();
    for (int i = tid; i < m; i += blockDim.x) col_s[beg + i] = lcol[i];
    if (tid < RPB) {
        int r = j * RPB + tid;
        if (r < N) rptr[r] = beg + lexc[tid];
    }
    if (j == 0 && tid == 0) rptr[N] = E;
}

// fused attention: per node (wave): pass1 = edge cosine sims (8 lanes/edge)
// stashed in LDS + wave-reduced row-sum; pass2 = w=exp(sim/rs), ballot-rank
// compaction into packed cw=(col, w), lend/dinv/selfc (= wself*di). No atomics.
__global__ void k_att(const float* __restrict__ fn,
                      const int* __restrict__ rptr, const int* __restrict__ col_s,
                      int2* __restrict__ cw, int* __restrict__ lend,
                      float* __restrict__ dinv, float* __restrict__ selfc, int n)
{
    __shared__ float ssim[4][ATT_CAP];
    __shared__ int   scol[4][ATT_CAP];
    int wib  = threadIdx.x >> 6;
    int wid  = blockIdx.x * 4 + wib;
    int lane = threadIdx.x & 63;
    if (wid >= n) return;
    int sub = lane & 7;
    int grp = lane >> 3;
    int beg = rptr[wid], end = rptr[wid + 1];
    int deg_all = end - beg;

    const float4* frp = (const float4*)(fn + (size_t)wid * 64);
    float4 a0 = frp[sub * 2], a1 = frp[sub * 2 + 1];

    // pass 1: sims + row-sum
    float rs_part = 0.0f;
    int ngrp = (deg_all + 7) >> 3;
    for (int g = 0; g < ngrp; ++g) {
        int li = g * 8 + grp;
        float s = 0.0f; int c = 0;
        bool valid = (li < deg_all);
        if (valid) {
            c = col_s[beg + li];
            const float4* fcp = (const float4*)(fn + (size_t)c * 64);
            float4 b0 = fcp[sub * 2], b1 = fcp[sub * 2 + 1];
            float p = a0.x * b0.x + a0.y * b0.y + a0.z * b0.z + a0.w * b0.w
                    + a1.x * b1.x + a1.y * b1.y + a1.z * b1.z + a1.w * b1.w;
            p += __shfl_xor(p, 1);
            p += __shfl_xor(p, 2);
            p += __shfl_xor(p, 4);
            s = (p < 0.1f) ? 0.0f : p;
        }
        if (sub == 0 && valid) {
            if (li < ATT_CAP) { ssim[wib][li] = s; scol[wib][li] = c; }
            if (s > 0.0f) rs_part += s;
        }
    }
#pragma unroll
    for (int off = 32; off > 0; off >>= 1) rs_part += __shfl_xor(rs_part, off);
    float denom = fmaxf(rs_part, 1e-12f);

    // pass 2: weights + live compaction (lane = edge index within 64-chunk)
    int   nlive = 0;
    float sw_lane = 0.0f;
    for (int base = 0; base < deg_all; base += 64) {
        int li = base + lane;
        bool valid = (li < deg_all);
        float s = 0.0f; int c = 0;
        if (valid) {
            if (li < ATT_CAP) { s = ssim[wib][li]; c = scol[wib][li]; }
            else {                           // astronomically rare: per-lane dot
                c = col_s[beg + li];
                const float* fr = fn + (size_t)wid * 64;
                const float* fc = fn + (size_t)c * 64;
                float p = 0.0f;
                for (int k = 0; k < 64; ++k) p += fr[k] * fc[k];
                s = (p < 0.1f) ? 0.0f : p;
            }
        }
        float w = (valid && s > 0.0f) ? expf(s / denom) : 0.0f;
        unsigned long long M = __ballot(w > 0.0f);
        int rank = __popcll(M & ((1ull << lane) - 1ull));
        if (w > 0.0f) {
            int2 pw; pw.x = c; pw.y = __float_as_int(w);
            cw[beg + nlive + rank] = pw;
            sw_lane += w;
        }
        nlive += __popcll(M);
    }
#pragma unroll
    for (int off = 32; off > 0; off >>= 1) sw_lane += __shfl_xor(sw_lane, off);

    if (lane == 0) {
        float wself = expf(1.0f / ((float)nlive + 1.0f));
        float D  = sw_lane + wself;
        float di = rsqrtf(fmaxf(D, 1e-12f));
        lend[wid]  = beg + nlive;
        dinv[wid]  = di;
        selfc[wid] = wself * di;   // self term applied to dinv-scaled table
    }
}

// dense GEMM out[N,F] = (fea[N,64] @ W[64,F]) * scale[r]; OutT element.
template <int F, typename InT, typename OutT>
__global__ void k_gemm(const InT* __restrict__ fea, const float* __restrict__ W,
                       const float* __restrict__ scale, OutT* __restrict__ out, int n)
{
    constexpr int R = 256 / F;
    __shared__ float sW[64 * F];
    __shared__ float sX[R * 64];
    int tid = threadIdx.x;
    for (int i = tid; i < 64 * F; i += 256) sW[i] = W[i];
    int base = blockIdx.x * R;
    for (int i = tid; i < R * 64; i += 256) {
        int rr = base + i / 64;
        sX[i] = (rr < n) ? (float)fea[(size_t)rr * 64 + (i & 63)] : 0.0f;
    }
    __syncthreads();
    int rl = tid / F, j = tid % F;
    if (rl >= R) return;
    int r = base + rl;
    if (r >= n) return;
    float acc = 0.0f;
#pragma unroll
    for (int k = 0; k < 64; ++k) acc = fmaf(sX[rl * 64 + k], sW[k * F + j], acc);
    out[(size_t)r * F + j] = (OutT)(acc * scale[r]);
}

// transposed live-edge aggregation, generic vec4 element (float4 / half4):
// 4 edges x 16 lanes; lane (eg,q) loads one vec4 of row c_eg at feature q*4.
// Returns per-lane (lane=feature) weighted sum via xor-reduce + transpose.
template <int F, typename Vec4>
__device__ inline float agg_core_t(const Vec4* __restrict__ hdv,
                                   const int2* __restrict__ cw,
                                   int beg, int lend_, int lane)
{
    int q  = lane & 15;
    int eg = lane >> 4;
    bool qact = (F == 64) ? true : (q < (F >> 2));
    float acc0 = 0.f, acc1 = 0.f, acc2 = 0.f, acc3 = 0.f;
    for (int base = beg; base < lend_; base += 64) {
        int idx = base + lane;
        int cv = 0; float wv = 0.0f;
        if (idx < lend_) { int2 pw = cw[idx]; cv = pw.x; wv = __int_as_float(pw.y); }
        int cnt = lend_ - base; if (cnt > 64) cnt = 64;
        for (int j = 0; j < cnt; j += 4) {
            int   c = __shfl(cv, j + eg);   // beyond-cnt lanes hold cv=0,wv=0
            float w = __shfl(wv, j + eg);
            if (qact) {
                Vec4 hv = hdv[(size_t)c * (F >> 2) + q];
                acc0 += w * (float)hv.x;
                acc1 += w * (float)hv.y;
                acc2 += w * (float)hv.z;
                acc3 += w * (float)hv.w;
            }
        }
    }
    acc0 += __shfl_xor(acc0, 16); acc0 += __shfl_xor(acc0, 32);
    acc1 += __shfl_xor(acc1, 16); acc1 += __shfl_xor(acc1, 32);
    acc2 += __shfl_xor(acc2, 16); acc2 += __shfl_xor(acc2, 32);
    acc3 += __shfl_xor(acc3, 16); acc3 += __shfl_xor(acc3, 32);
    int srcq = lane >> 2;
    float a0 = __shfl(acc0, srcq);
    float a1 = __shfl(acc1, srcq);
    float a2 = __shfl(acc2, srcq);
    float a3 = __shfl(acc3, srcq);
    int k = lane & 3;
    return (k == 0) ? a0 : (k == 1) ? a1 : (k == 2) ? a2 : a3;
}

// layer-1 aggregation over fp32 dinv-scaled table + relu; emits hrelu16 + fnh
__global__ void k_agg64(const float* __restrict__ hd, const int2* __restrict__ cw,
                        const float* __restrict__ dinv, const float* __restrict__ selfc,
                        const float* __restrict__ b, const int* __restrict__ row_ptr,
                        const int* __restrict__ lend,
                        _Float16* __restrict__ hrelu16, float* __restrict__ fnh, int n)
{
    int gid  = blockIdx.x * blockDim.x + threadIdx.x;
    int wid  = gid >> 6;
    int lane = threadIdx.x & 63;
    if (wid >= n) return;
    int beg = row_ptr[wid], le = lend[wid];
    float accf = agg_core_t<64>((const float4*)hd, cw, beg, le, lane);
    float hs  = hd[(size_t)wid * 64 + lane];  // = h*di
    float v = dinv[wid] * accf + selfc[wid] * hs + b[lane];
    v = fmaxf(v, 0.0f); // relu
    hrelu16[(size_t)wid * 64 + lane] = (_Float16)v;
    float s = v * v;
#pragma unroll
    for (int off = 32; off > 0; off >>= 1) s += __shfl_xor(s, off);
    float inv = 1.0f / fmaxf(sqrtf(s), 1e-12f);
    fnh[(size_t)wid * 64 + lane] = v * inv;
}

// layer-2 aggregation (F=40, fp16 table) + bias + log_softmax -> output.
__global__ void k_agg40_lsm(const _Float16* __restrict__ hd2, const int2* __restrict__ cw,
                            const float* __restrict__ dinv, const float* __restrict__ selfc,
                            const float* __restrict__ b, const int* __restrict__ row_ptr,
                            const int* __restrict__ lend,
                            float* __restrict__ out, int n)
{
    constexpr int F = 40;
    int gid  = blockIdx.x * blockDim.x + threadIdx.x;
    int wid  = gid >> 6;
    int lane = threadIdx.x & 63;
    if (wid >= n) return;
    int beg = row_ptr[wid], le = lend[wid];
    float accf = agg_core_t<F>((const half4*)hd2, cw, beg, le, lane);
    bool active = (lane < F);
    float v = 0.0f;
    if (active) {
        float hs = (float)hd2[(size_t)wid * F + lane];
        v = dinv[wid] * accf + selfc[wid] * hs + b[lane];
    }
    float m = active ? v : -__builtin_inff();
#pragma unroll
    for (int off = 32; off > 0; off >>= 1) m = fmaxf(m, __shfl_xor(m, off));
    float ex = active ? expf(v - m) : 0.0f;
    float s = ex;
#pragma unroll
    for (int off = 32; off > 0; off >>= 1) s += __shfl_xor(s, off);
    if (active) out[(size_t)wid * F + lane] = v - m - logf(s);
}

extern "C" void kernel_launch(void* const* d_in, const int* in_sizes, int n_in,
                              void* d_out, int out_size, void* d_ws, size_t ws_size,
                              hipStream_t stream)
{
    const float* x  = (const float*)d_in[0];
    const int*   ei = (const int*)d_in[1];
    const float* W1 = (const float*)d_in[2];
    const float* b1 = (const float*)d_in[3];
    const float* W2 = (const float*)d_in[4];
    const float* b2 = (const float*)d_in[5];
    float* out = (float*)d_out;

    const int N = in_sizes[0] / 64;   // 50000
    const int E = in_sizes[1] / 2;    // 800000
    const int* row = ei;
    const int* col = ei + E;

    const int nblkA = (E + EPB - 1) / EPB;       // edge blocks for bucket sort
    const int nbuck = (N + RPB - 1) / RPB;       // buckets (rows/128)

    char* p = (char*)d_ws;
    auto alloc = [&](size_t bytes) -> char* {
        char* r = p; p += (bytes + 255) & ~(size_t)255; return r;
    };
    float*     fn     = (float*)alloc((size_t)N * 64 * 4);     // normalized x
    float*     dinv   = (float*)alloc((size_t)N * 4);
    float*     selfc  = (float*)alloc((size_t)N * 4);
    float*     hd1    = (float*)alloc((size_t)N * 64 * 4);     // (x@W1)*di (fp32)
    _Float16*  hrelu  = (_Float16*)alloc((size_t)N * 64 * 2);  // relu out (fp16)
    _Float16*  hd2    = (_Float16*)alloc((size_t)N * 40 * 2);  // (hrelu@W2)*di2 (fp16)
    float*     fnh    = (float*)alloc((size_t)N * 64 * 4);     // normalized hrelu
    int*       rptr   = (int*)alloc((size_t)(N + 1) * 4);
    int*       lendv  = (int*)alloc((size_t)N * 4);
    int*       col_s  = (int*)alloc((size_t)E * 4);
    int2*      cw     = (int2*)alloc((size_t)E * 8);           // packed (col,w)
    int*       ebuf   = (int*)alloc((size_t)nbuck * CAPB * 4); // slack-segmented
    int*       gcur   = (int*)alloc((size_t)nbuck * 4);

    const int TB = 256;
    int blk_nodeWave = (N * 64 + TB - 1) / TB;
    int blk_node4    = (N + 3) / 4;

    hipMemsetAsync(gcur, 0, (size_t)nbuck * 4, stream);

    // ---- CSR build (2 kernels: slack scatter + per-bucket finalize)
    k_bscat<<<nblkA, TB, 0, stream>>>(row, col, gcur, ebuf, E, nbuck);
    k_csr<<<nbuck, TB, 0, stream>>>(ebuf, gcur, rptr, col_s, N, E, nbuck);

    // ---- layer 1
    k_normfn<<<blk_nodeWave, TB, 0, stream>>>(x, fn, N);
    k_att<<<blk_node4, TB, 0, stream>>>(fn, rptr, col_s, cw, lendv, dinv, selfc, N);
    k_gemm<64, float, float><<<(N + 3) / 4, TB, 0, stream>>>(x, W1, dinv, hd1, N);
    k_agg64<<<blk_nodeWave, TB, 0, stream>>>(hd1, cw, dinv, selfc, b1,
                                             rptr, lendv, hrelu, fnh, N);

    // ---- layer 2
    k_att<<<blk_node4, TB, 0, stream>>>(fnh, rptr, col_s, cw, lendv, dinv, selfc, N);
    k_gemm<40, _Float16, _Float16><<<(N + 5) / 6, TB, 0, stream>>>(hrelu, W2, dinv, hd2, N);
    k_agg40_lsm<<<blk_nodeWave, TB, 0, stream>>>(hd2, cw, dinv, selfc, b2,
                                                 rptr, lendv, out, N);
}

// Round 12
// 268.352 us; speedup vs baseline: 1.0687x; 1.0205x over previous
//
#include <hip/hip_runtime.h>
#include <math.h>

// ---------------------------------------------------------------------------
// GuardNet: 2-layer attention-weighted GCN.
// R12: (a) k_bscat edge stash uses fixed-unroll compile-time-indexed arrays
// (dynamic ne-index forced scratch spill); (b) k_att pass-1 switched to
// 4 lanes/edge (16 edges/iter): 4 independent float4 loads per lane, 2-step
// shuffle reduce, single iteration for deg<=16 (median). Rest = R11.
// ---------------------------------------------------------------------------

#define ATT_CAP 96      // per-node LDS sim stash; deg>CAP falls back to recompute
#define EPB     2048    // edges per bucket-sort block (= 8 per thread at TB=256)
#define RPB     128     // rows per bucket (bucket = row>>7)
#define NBUCK_MAX 512
#define CAPB    4096    // slack per bucket (mean 2048, sigma~45 -> never hit)

typedef _Float16 half4 __attribute__((ext_vector_type(4)));

// normalize rows: fn[i] = x[i] / max(||x[i]||,1e-12). one wave per node.
__global__ void k_normfn(const float* __restrict__ fea, float* __restrict__ fn, int n)
{
    int gid  = blockIdx.x * blockDim.x + threadIdx.x;
    int wid  = gid >> 6;
    int lane = threadIdx.x & 63;
    if (wid >= n) return;
    float v = fea[(size_t)wid * 64 + lane];
    float s = v * v;
#pragma unroll
    for (int off = 32; off > 0; off >>= 1) s += __shfl_xor(s, off);
    float inv = 1.0f / fmaxf(sqrtf(s), 1e-12f);
    fn[(size_t)wid * 64 + lane] = v * inv;
}

// scatter into slack-segmented ebuf: LDS hist over register-stashed edges
// (fixed unroll -> no scratch), one global atomicAdd per (block,bucket)
// reserves a range at j*CAPB + gcur[j], then LDS-cursor scatter of packed
// (localrow<<16 | col). After the grid, gcur[j] == bucket j's edge count.
__global__ void k_bscat(const int* __restrict__ row, const int* __restrict__ col,
                        int* __restrict__ gcur, int* __restrict__ ebuf, int E, int nbuck)
{
    __shared__ int lh[NBUCK_MAX];
    __shared__ int lbase[NBUCK_MAX];
    int b = blockIdx.x;
    int ebeg = b * EPB;
    int rr[8], cc[8];
    for (int i = threadIdx.x; i < nbuck; i += blockDim.x) lh[i] = 0;
    __syncthreads();
#pragma unroll
    for (int k = 0; k < 8; ++k) {
        int e = ebeg + k * 256 + threadIdx.x;
        bool v = (e < E);
        int r = v ? row[e] : -1;
        int c = v ? col[e] : 0;
        rr[k] = r; cc[k] = c;
        if (v) atomicAdd(&lh[r >> 7], 1);
    }
    __syncthreads();
    for (int i = threadIdx.x; i < nbuck; i += blockDim.x) {
        int cnt = lh[i];
        if (cnt) lbase[i] = i * CAPB + atomicAdd(gcur + i, cnt);
        lh[i] = 0;                       // reuse as local cursor
    }
    __syncthreads();
#pragma unroll
    for (int k = 0; k < 8; ++k) {
        int r = rr[k];
        if (r >= 0) {
            int j = r >> 7;
            int pos = lbase[j] + atomicAdd(&lh[j], 1);
            ebuf[pos] = ((r & (RPB - 1)) << 16) | cc[k];
        }
    }
}

// one block per bucket: computes own exclusive prefix of gcur, LDS row-binning
// of its slack segment, coalesced col_s + rptr writes.
__global__ void k_csr(const int* __restrict__ ebuf, const int* __restrict__ gcur,
                      int* __restrict__ rptr, int* __restrict__ col_s,
                      int N, int E, int nbuck)
{
    __shared__ int pk[CAPB];
    __shared__ int lcol[CAPB];
    __shared__ int lcnt[RPB], lexc[RPB], lcur[RPB];
    __shared__ int spart[4];
    int j = blockIdx.x;
    int tid = threadIdx.x;
    int lane = tid & 63, wave = tid >> 6;

    // exclusive prefix: beg = sum(gcur[0..j))
    int part = 0;
    for (int i = tid; i < j; i += blockDim.x) part += gcur[i];
#pragma unroll
    for (int off = 32; off > 0; off >>= 1) part += __shfl_xor(part, off);
    if (lane == 0) spart[wave] = part;
    if (tid < RPB) lcnt[tid] = 0;
    __syncthreads();
    int beg = spart[0] + spart[1] + spart[2] + spart[3];
    int m = gcur[j]; if (m > CAPB) m = CAPB;     // never hit

    const int* seg = ebuf + (size_t)j * CAPB;
    for (int i = tid; i < m; i += blockDim.x) pk[i] = seg[i];
    __syncthreads();
    for (int i = tid; i < m; i += blockDim.x) atomicAdd(&lcnt[pk[i] >> 16], 1);
    __syncthreads();
    if (tid < 64) {                    // wave 0 scans 128 counts (2 per lane)
        int a = lcnt[2 * tid], b2 = lcnt[2 * tid + 1];
        int s = a + b2;
        int incl = s;
#pragma unroll
        for (int off = 1; off < 64; off <<= 1) {
            int v = __shfl_up(incl, off);
            if (tid >= off) incl += v;
        }
        int base = incl - s;
        lexc[2 * tid] = base;     lexc[2 * tid + 1] = base + a;
        lcur[2 * tid] = base;     lcur[2 * tid + 1] = base + a;
    }
    __syncthreads();
    for (int i = tid; i < m; i += blockDim.x) {
        int v = pk[i];
        int p = atomicAdd(&lcur[v >> 16], 1);
        lcol[p] = v & 0xFFFF;
    }
    __syncthreads();
    for (int i = tid; i < m; i += blockDim.x) col_s[beg + i] = lcol[i];
    if (tid < RPB) {
        int r = j * RPB + tid;
        if (r < N) rptr[r] = beg + lexc[tid];
    }
    if (j == 0 && tid == 0) rptr[N] = E;
}

// fused attention: per node (wave): pass1 = edge cosine sims (4 lanes/edge,
// 16 edges/iter) stashed in LDS + wave-reduced row-sum; pass2 = w=exp(sim/rs),
// ballot-rank compaction into packed cw=(col,w), lend/dinv/selfc. No atomics.
__global__ void k_att(const float* __restrict__ fn,
                      const int* __restrict__ rptr, const int* __restrict__ col_s,
                      int2* __restrict__ cw, int* __restrict__ lend,
                      float* __restrict__ dinv, float* __restrict__ selfc, int n)
{
    __shared__ float ssim[4][ATT_CAP];
    __shared__ int   scol[4][ATT_CAP];
    int wib  = threadIdx.x >> 6;
    int wid  = blockIdx.x * 4 + wib;
    int lane = threadIdx.x & 63;
    if (wid >= n) return;
    int sub = lane & 3;       // lane within 4-lane edge group
    int grp = lane >> 2;      // edge group 0..15
    int beg = rptr[wid], end = rptr[wid + 1];
    int deg_all = end - beg;

    const float4* frp = (const float4*)(fn + (size_t)wid * 64);
    float4 a0 = frp[sub], a1 = frp[sub + 4], a2 = frp[sub + 8], a3 = frp[sub + 12];

    // pass 1: sims + row-sum (16 edges per iteration)
    float rs_part = 0.0f;
    int ngrp = (deg_all + 15) >> 4;
    for (int g = 0; g < ngrp; ++g) {
        int li = g * 16 + grp;
        float s = 0.0f; int c = 0;
        bool valid = (li < deg_all);
        if (valid) {
            c = col_s[beg + li];
            const float4* fcp = (const float4*)(fn + (size_t)c * 64);
            float4 b0 = fcp[sub], b1 = fcp[sub + 4], b2 = fcp[sub + 8], b3 = fcp[sub + 12];
            float p = a0.x * b0.x + a0.y * b0.y + a0.z * b0.z + a0.w * b0.w
                    + a1.x * b1.x + a1.y * b1.y + a1.z * b1.z + a1.w * b1.w
                    + a2.x * b2.x + a2.y * b2.y + a2.z * b2.z + a2.w * b2.w
                    + a3.x * b3.x + a3.y * b3.y + a3.z * b3.z + a3.w * b3.w;
            p += __shfl_xor(p, 1);
            p += __shfl_xor(p, 2);
            s = (p < 0.1f) ? 0.0f : p;
        }
        if (sub == 0 && valid) {
            if (li < ATT_CAP) { ssim[wib][li] = s; scol[wib][li] = c; }
            if (s > 0.0f) rs_part += s;
        }
    }
#pragma unroll
    for (int off = 32; off > 0; off >>= 1) rs_part += __shfl_xor(rs_part, off);
    float denom = fmaxf(rs_part, 1e-12f);

    // pass 2: weights + live compaction (lane = edge index within 64-chunk)
    int   nlive = 0;
    float sw_lane = 0.0f;
    for (int base = 0; base < deg_all; base += 64) {
        int li = base + lane;
        bool valid = (li < deg_all);
        float s = 0.0f; int c = 0;
        if (valid) {
            if (li < ATT_CAP) { s = ssim[wib][li]; c = scol[wib][li]; }
            else {                           // astronomically rare: per-lane dot
                c = col_s[beg + li];
                const float* fr = fn + (size_t)wid * 64;
                const float* fc = fn + (size_t)c * 64;
                float p = 0.0f;
                for (int k = 0; k < 64; ++k) p += fr[k] * fc[k];
                s = (p < 0.1f) ? 0.0f : p;
            }
        }
        float w = (valid && s > 0.0f) ? expf(s / denom) : 0.0f;
        unsigned long long M = __ballot(w > 0.0f);
        int rank = __popcll(M & ((1ull << lane) - 1ull));
        if (w > 0.0f) {
            int2 pw; pw.x = c; pw.y = __float_as_int(w);
            cw[beg + nlive + rank] = pw;
            sw_lane += w;
        }
        nlive += __popcll(M);
    }
#pragma unroll
    for (int off = 32; off > 0; off >>= 1) sw_lane += __shfl_xor(sw_lane, off);

    if (lane == 0) {
        float wself = expf(1.0f / ((float)nlive + 1.0f));
        float D  = sw_lane + wself;
        float di = rsqrtf(fmaxf(D, 1e-12f));
        lend[wid]  = beg + nlive;
        dinv[wid]  = di;
        selfc[wid] = wself * di;   // self term applied to dinv-scaled table
    }
}

// dense GEMM out[N,F] = (fea[N,64] @ W[64,F]) * scale[r]; OutT element.
template <int F, typename InT, typename OutT>
__global__ void k_gemm(const InT* __restrict__ fea, const float* __restrict__ W,
                       const float* __restrict__ scale, OutT* __restrict__ out, int n)
{
    constexpr int R = 256 / F;
    __shared__ float sW[64 * F];
    __shared__ float sX[R * 64];
    int tid = threadIdx.x;
    for (int i = tid; i < 64 * F; i += 256) sW[i] = W[i];
    int base = blockIdx.x * R;
    for (int i = tid; i < R * 64; i += 256) {
        int rr = base + i / 64;
        sX[i] = (rr < n) ? (float)fea[(size_t)rr * 64 + (i & 63)] : 0.0f;
    }
    __syncthreads();
    int rl = tid / F, j = tid % F;
    if (rl >= R) return;
    int r = base + rl;
    if (r >= n) return;
    float acc = 0.0f;
#pragma unroll
    for (int k = 0; k < 64; ++k) acc = fmaf(sX[rl * 64 + k], sW[k * F + j], acc);
    out[(size_t)r * F + j] = (OutT)(acc * scale[r]);
}

// transposed live-edge aggregation, generic vec4 element (float4 / half4):
// 4 edges x 16 lanes; lane (eg,q) loads one vec4 of row c_eg at feature q*4.
// Returns per-lane (lane=feature) weighted sum via xor-reduce + transpose.
template <int F, typename Vec4>
__device__ inline float agg_core_t(const Vec4* __restrict__ hdv,
                                   const int2* __restrict__ cw,
                                   int beg, int lend_, int lane)
{
    int q  = lane & 15;
    int eg = lane >> 4;
    bool qact = (F == 64) ? true : (q < (F >> 2));
    float acc0 = 0.f, acc1 = 0.f, acc2 = 0.f, acc3 = 0.f;
    for (int base = beg; base < lend_; base += 64) {
        int idx = base + lane;
        int cv = 0; float wv = 0.0f;
        if (idx < lend_) { int2 pw = cw[idx]; cv = pw.x; wv = __int_as_float(pw.y); }
        int cnt = lend_ - base; if (cnt > 64) cnt = 64;
        for (int j = 0; j < cnt; j += 4) {
            int   c = __shfl(cv, j + eg);   // beyond-cnt lanes hold cv=0,wv=0
            float w = __shfl(wv, j + eg);
            if (qact) {
                Vec4 hv = hdv[(size_t)c * (F >> 2) + q];
                acc0 += w * (float)hv.x;
                acc1 += w * (float)hv.y;
                acc2 += w * (float)hv.z;
                acc3 += w * (float)hv.w;
            }
        }
    }
    acc0 += __shfl_xor(acc0, 16); acc0 += __shfl_xor(acc0, 32);
    acc1 += __shfl_xor(acc1, 16); acc1 += __shfl_xor(acc1, 32);
    acc2 += __shfl_xor(acc2, 16); acc2 += __shfl_xor(acc2, 32);
    acc3 += __shfl_xor(acc3, 16); acc3 += __shfl_xor(acc3, 32);
    int srcq = lane >> 2;
    float a0 = __shfl(acc0, srcq);
    float a1 = __shfl(acc1, srcq);
    float a2 = __shfl(acc2, srcq);
    float a3 = __shfl(acc3, srcq);
    int k = lane & 3;
    return (k == 0) ? a0 : (k == 1) ? a1 : (k == 2) ? a2 : a3;
}

// layer-1 aggregation over fp32 dinv-scaled table + relu; emits hrelu16 + fnh
__global__ void k_agg64(const float* __restrict__ hd, const int2* __restrict__ cw,
                        const float* __restrict__ dinv, const float* __restrict__ selfc,
                        const float* __restrict__ b, const int* __restrict__ row_ptr,
                        const int* __restrict__ lend,
                        _Float16* __restrict__ hrelu16, float* __restrict__ fnh, int n)
{
    int gid  = blockIdx.x * blockDim.x + threadIdx.x;
    int wid  = gid >> 6;
    int lane = threadIdx.x & 63;
    if (wid >= n) return;
    int beg = row_ptr[wid], le = lend[wid];
    float accf = agg_core_t<64>((const float4*)hd, cw, beg, le, lane);
    float hs  = hd[(size_t)wid * 64 + lane];  // = h*di
    float v = dinv[wid] * accf + selfc[wid] * hs + b[lane];
    v = fmaxf(v, 0.0f); // relu
    hrelu16[(size_t)wid * 64 + lane] = (_Float16)v;
    float s = v * v;
#pragma unroll
    for (int off = 32; off > 0; off >>= 1) s += __shfl_xor(s, off);
    float inv = 1.0f / fmaxf(sqrtf(s), 1e-12f);
    fnh[(size_t)wid * 64 + lane] = v * inv;
}

// layer-2 aggregation (F=40, fp16 table) + bias + log_softmax -> output.
__global__ void k_agg40_lsm(const _Float16* __restrict__ hd2, const int2* __restrict__ cw,
                            const float* __restrict__ dinv, const float* __restrict__ selfc,
                            const float* __restrict__ b, const int* __restrict__ row_ptr,
                            const int* __restrict__ lend,
                            float* __restrict__ out, int n)
{
    constexpr int F = 40;
    int gid  = blockIdx.x * blockDim.x + threadIdx.x;
    int wid  = gid >> 6;
    int lane = threadIdx.x & 63;
    if (wid >= n) return;
    int beg = row_ptr[wid], le = lend[wid];
    float accf = agg_core_t<F>((const half4*)hd2, cw, beg, le, lane);
    bool active = (lane < F);
    float v = 0.0f;
    if (active) {
        float hs = (float)hd2[(size_t)wid * F + lane];
        v = dinv[wid] * accf + selfc[wid] * hs + b[lane];
    }
    float m = active ? v : -__builtin_inff();
#pragma unroll
    for (int off = 32; off > 0; off >>= 1) m = fmaxf(m, __shfl_xor(m, off));
    float ex = active ? expf(v - m) : 0.0f;
    float s = ex;
#pragma unroll
    for (int off = 32; off > 0; off >>= 1) s += __shfl_xor(s, off);
    if (active) out[(size_t)wid * F + lane] = v - m - logf(s);
}

extern "C" void kernel_launch(void* const* d_in, const int* in_sizes, int n_in,
                              void* d_out, int out_size, void* d_ws, size_t ws_size,
                              hipStream_t stream)
{
    const float* x  = (const float*)d_in[0];
    const int*   ei = (const int*)d_in[1];
    const float* W1 = (const float*)d_in[2];
    const float* b1 = (const float*)d_in[3];
    const float* W2 = (const float*)d_in[4];
    const float* b2 = (const float*)d_in[5];
    float* out = (float*)d_out;

    const int N = in_sizes[0] / 64;   // 50000
    const int E = in_sizes[1] / 2;    // 800000
    const int* row = ei;
    const int* col = ei + E;

    const int nblkA = (E + EPB - 1) / EPB;       // edge blocks for bucket sort
    const int nbuck = (N + RPB - 1) / RPB;       // buckets (rows/128)

    char* p = (char*)d_ws;
    auto alloc = [&](size_t bytes) -> char* {
        char* r = p; p += (bytes + 255) & ~(size_t)255; return r;
    };
    float*     fn     = (float*)alloc((size_t)N * 64 * 4);     // normalized x
    float*     dinv   = (float*)alloc((size_t)N * 4);
    float*     selfc  = (float*)alloc((size_t)N * 4);
    float*     hd1    = (float*)alloc((size_t)N * 64 * 4);     // (x@W1)*di (fp32)
    _Float16*  hrelu  = (_Float16*)alloc((size_t)N * 64 * 2);  // relu out (fp16)
    _Float16*  hd2    = (_Float16*)alloc((size_t)N * 40 * 2);  // (hrelu@W2)*di2 (fp16)
    float*     fnh    = (float*)alloc((size_t)N * 64 * 4);     // normalized hrelu
    int*       rptr   = (int*)alloc((size_t)(N + 1) * 4);
    int*       lendv  = (int*)alloc((size_t)N * 4);
    int*       col_s  = (int*)alloc((size_t)E * 4);
    int2*      cw     = (int2*)alloc((size_t)E * 8);           // packed (col,w)
    int*       ebuf   = (int*)alloc((size_t)nbuck * CAPB * 4); // slack-segmented
    int*       gcur   = (int*)alloc((size_t)nbuck * 4);

    const int TB = 256;
    int blk_nodeWave = (N * 64 + TB - 1) / TB;
    int blk_node4    = (N + 3) / 4;

    hipMemsetAsync(gcur, 0, (size_t)nbuck * 4, stream);

    // ---- CSR build (2 kernels: slack scatter + per-bucket finalize)
    k_bscat<<<nblkA, TB, 0, stream>>>(row, col, gcur, ebuf, E, nbuck);
    k_csr<<<nbuck, TB, 0, stream>>>(ebuf, gcur, rptr, col_s, N, E, nbuck);

    // ---- layer 1
    k_normfn<<<blk_nodeWave, TB, 0, stream>>>(x, fn, N);
    k_att<<<blk_node4, TB, 0, stream>>>(fn, rptr, col_s, cw, lendv, dinv, selfc, N);
    k_gemm<64, float, float><<<(N + 3) / 4, TB, 0, stream>>>(x, W1, dinv, hd1, N);
    k_agg64<<<blk_nodeWave, TB, 0, stream>>>(hd1, cw, dinv, selfc, b1,
                                             rptr, lendv, hrelu, fnh, N);

    // ---- layer 2
    k_att<<<blk_node4, TB, 0, stream>>>(fnh, rptr, col_s, cw, lendv, dinv, selfc, N);
    k_gemm<40, _Float16, _Float16><<<(N + 5) / 6, TB, 0, stream>>>(hrelu, W2, dinv, hd2, N);
    k_agg40_lsm<<<blk_nodeWave, TB, 0, stream>>>(hd2, cw, dinv, selfc, b2,
                                                 rptr, lendv, out, N);
}

// Round 13
// 262.324 us; speedup vs baseline: 1.0933x; 1.0230x over previous
//
#include <hip/hip_runtime.h>
#include <math.h>

// ---------------------------------------------------------------------------
// GuardNet: 2-layer attention-weighted GCN.
// R13: kernel-count diet (9+memset -> 7+memset):
//  - k_bscat_norm: bucket scatter fused with x row-normalization (indep work).
//  - k_agg64: gemm40 matmul fused into epilogue (wave holds v; LDS-staged W2;
//    40 lanes x 64-MAC dots) -> writes g2 fp32. hrelu buffer + gemm40 gone;
//    v@W2 input is now fp32 (more accurate than old fp16 hrelu path).
//  - k_att (layer 2): di2 scaling of g2 -> hd2 fp16 fused into epilogue
//    (di is wave-uniform post-reduction).
// Rest = R12 (slack-segmented bucket CSR, fp32 hd1, transposed agg).
// ---------------------------------------------------------------------------

#define ATT_CAP 96      // per-node LDS sim stash; deg>CAP falls back to recompute
#define EPB     2048    // edges per bucket-sort block (= 8 per thread at TB=256)
#define RPB     128     // rows per bucket (bucket = row>>7)
#define NBUCK_MAX 512
#define CAPB    4096    // slack per bucket (mean 2048, sigma~45 -> never hit)

typedef _Float16 half4 __attribute__((ext_vector_type(4)));

// fused: blocks [0,nblkA) = bucket scatter; blocks [nblkA,..) = fn row norm.
__global__ void k_bscat_norm(const int* __restrict__ row, const int* __restrict__ col,
                             int* __restrict__ gcur, int* __restrict__ ebuf,
                             int E, int nbuck, int nblkA,
                             const float* __restrict__ x, float* __restrict__ fn, int N)
{
    __shared__ int lh[NBUCK_MAX];
    __shared__ int lbase[NBUCK_MAX];
    if ((int)blockIdx.x >= nblkA) {
        // ---- normfn body
        int gid  = (blockIdx.x - nblkA) * blockDim.x + threadIdx.x;
        int wid  = gid >> 6;
        int lane = threadIdx.x & 63;
        if (wid >= N) return;
        float v = x[(size_t)wid * 64 + lane];
        float s = v * v;
#pragma unroll
        for (int off = 32; off > 0; off >>= 1) s += __shfl_xor(s, off);
        float inv = 1.0f / fmaxf(sqrtf(s), 1e-12f);
        fn[(size_t)wid * 64 + lane] = v * inv;
        return;
    }
    // ---- bucket scatter body
    int b = blockIdx.x;
    int ebeg = b * EPB;
    int rr[8], cc[8];
    for (int i = threadIdx.x; i < nbuck; i += blockDim.x) lh[i] = 0;
    __syncthreads();
#pragma unroll
    for (int k = 0; k < 8; ++k) {
        int e = ebeg + k * 256 + threadIdx.x;
        bool v = (e < E);
        int r = v ? row[e] : -1;
        int c = v ? col[e] : 0;
        rr[k] = r; cc[k] = c;
        if (v) atomicAdd(&lh[r >> 7], 1);
    }
    __syncthreads();
    for (int i = threadIdx.x; i < nbuck; i += blockDim.x) {
        int cnt = lh[i];
        if (cnt) lbase[i] = i * CAPB + atomicAdd(gcur + i, cnt);
        lh[i] = 0;                       // reuse as local cursor
    }
    __syncthreads();
#pragma unroll
    for (int k = 0; k < 8; ++k) {
        int r = rr[k];
        if (r >= 0) {
            int j = r >> 7;
            int pos = lbase[j] + atomicAdd(&lh[j], 1);
            ebuf[pos] = ((r & (RPB - 1)) << 16) | cc[k];
        }
    }
}

// one block per bucket: computes own exclusive prefix of gcur, LDS row-binning
// of its slack segment, coalesced col_s + rptr writes.
__global__ void k_csr(const int* __restrict__ ebuf, const int* __restrict__ gcur,
                      int* __restrict__ rptr, int* __restrict__ col_s,
                      int N, int E, int nbuck)
{
    __shared__ int pk[CAPB];
    __shared__ int lcol[CAPB];
    __shared__ int lcnt[RPB], lexc[RPB], lcur[RPB];
    __shared__ int spart[4];
    int j = blockIdx.x;
    int tid = threadIdx.x;
    int lane = tid & 63, wave = tid >> 6;

    // exclusive prefix: beg = sum(gcur[0..j))
    int part = 0;
    for (int i = tid; i < j; i += blockDim.x) part += gcur[i];
#pragma unroll
    for (int off = 32; off > 0; off >>= 1) part += __shfl_xor(part, off);
    if (lane == 0) spart[wave] = part;
    if (tid < RPB) lcnt[tid] = 0;
    __syncthreads();
    int beg = spart[0] + spart[1] + spart[2] + spart[3];
    int m = gcur[j]; if (m > CAPB) m = CAPB;     // never hit

    const int* seg = ebuf + (size_t)j * CAPB;
    for (int i = tid; i < m; i += blockDim.x) pk[i] = seg[i];
    __syncthreads();
    for (int i = tid; i < m; i += blockDim.x) atomicAdd(&lcnt[pk[i] >> 16], 1);
    __syncthreads();
    if (tid < 64) {                    // wave 0 scans 128 counts (2 per lane)
        int a = lcnt[2 * tid], b2 = lcnt[2 * tid + 1];
        int s = a + b2;
        int incl = s;
#pragma unroll
        for (int off = 1; off < 64; off <<= 1) {
            int v = __shfl_up(incl, off);
            if (tid >= off) incl += v;
        }
        int base = incl - s;
        lexc[2 * tid] = base;     lexc[2 * tid + 1] = base + a;
        lcur[2 * tid] = base;     lcur[2 * tid + 1] = base + a;
    }
    __syncthreads();
    for (int i = tid; i < m; i += blockDim.x) {
        int v = pk[i];
        int p = atomicAdd(&lcur[v >> 16], 1);
        lcol[p] = v & 0xFFFF;
    }
    __syncthreads();
    for (int i = tid; i < m; i += blockDim.x) col_s[beg + i] = lcol[i];
    if (tid < RPB) {
        int r = j * RPB + tid;
        if (r < N) rptr[r] = beg + lexc[tid];
    }
    if (j == 0 && tid == 0) rptr[N] = E;
}

// fused attention: per node (wave): pass1 = edge cosine sims (4 lanes/edge,
// 16 edges/iter) stashed in LDS + wave-reduced row-sum; pass2 = w=exp(sim/rs),
// ballot-rank compaction into packed cw=(col,w), lend/dinv/selfc. No atomics.
// Optional layer-2 epilogue: hd2[wid] = g2[wid] * di (di wave-uniform).
__global__ void k_att(const float* __restrict__ fn,
                      const int* __restrict__ rptr, const int* __restrict__ col_s,
                      int2* __restrict__ cw, int* __restrict__ lend,
                      float* __restrict__ dinv, float* __restrict__ selfc,
                      const float* __restrict__ g2, _Float16* __restrict__ hd2, int n)
{
    __shared__ float ssim[4][ATT_CAP];
    __shared__ int   scol[4][ATT_CAP];
    int wib  = threadIdx.x >> 6;
    int wid  = blockIdx.x * 4 + wib;
    int lane = threadIdx.x & 63;
    if (wid >= n) return;
    int sub = lane & 3;       // lane within 4-lane edge group
    int grp = lane >> 2;      // edge group 0..15
    int beg = rptr[wid], end = rptr[wid + 1];
    int deg_all = end - beg;

    const float4* frp = (const float4*)(fn + (size_t)wid * 64);
    float4 a0 = frp[sub], a1 = frp[sub + 4], a2 = frp[sub + 8], a3 = frp[sub + 12];

    // pass 1: sims + row-sum (16 edges per iteration)
    float rs_part = 0.0f;
    int ngrp = (deg_all + 15) >> 4;
    for (int g = 0; g < ngrp; ++g) {
        int li = g * 16 + grp;
        float s = 0.0f; int c = 0;
        bool valid = (li < deg_all);
        if (valid) {
            c = col_s[beg + li];
            const float4* fcp = (const float4*)(fn + (size_t)c * 64);
            float4 b0 = fcp[sub], b1 = fcp[sub + 4], b2 = fcp[sub + 8], b3 = fcp[sub + 12];
            float p = a0.x * b0.x + a0.y * b0.y + a0.z * b0.z + a0.w * b0.w
                    + a1.x * b1.x + a1.y * b1.y + a1.z * b1.z + a1.w * b1.w
                    + a2.x * b2.x + a2.y * b2.y + a2.z * b2.z + a2.w * b2.w
                    + a3.x * b3.x + a3.y * b3.y + a3.z * b3.z + a3.w * b3.w;
            p += __shfl_xor(p, 1);
            p += __shfl_xor(p, 2);
            s = (p < 0.1f) ? 0.0f : p;
        }
        if (sub == 0 && valid) {
            if (li < ATT_CAP) { ssim[wib][li] = s; scol[wib][li] = c; }
            if (s > 0.0f) rs_part += s;
        }
    }
#pragma unroll
    for (int off = 32; off > 0; off >>= 1) rs_part += __shfl_xor(rs_part, off);
    float denom = fmaxf(rs_part, 1e-12f);

    // pass 2: weights + live compaction (lane = edge index within 64-chunk)
    int   nlive = 0;
    float sw_lane = 0.0f;
    for (int base = 0; base < deg_all; base += 64) {
        int li = base + lane;
        bool valid = (li < deg_all);
        float s = 0.0f; int c = 0;
        if (valid) {
            if (li < ATT_CAP) { s = ssim[wib][li]; c = scol[wib][li]; }
            else {                           // astronomically rare: per-lane dot
                c = col_s[beg + li];
                const float* fr = fn + (size_t)wid * 64;
                const float* fc = fn + (size_t)c * 64;
                float p = 0.0f;
                for (int k = 0; k < 64; ++k) p += fr[k] * fc[k];
                s = (p < 0.1f) ? 0.0f : p;
            }
        }
        float w = (valid && s > 0.0f) ? expf(s / denom) : 0.0f;
        unsigned long long M = __ballot(w > 0.0f);
        int rank = __popcll(M & ((1ull << lane) - 1ull));
        if (w > 0.0f) {
            int2 pw; pw.x = c; pw.y = __float_as_int(w);
            cw[beg + nlive + rank] = pw;
            sw_lane += w;
        }
        nlive += __popcll(M);
    }
#pragma unroll
    for (int off = 32; off > 0; off >>= 1) sw_lane += __shfl_xor(sw_lane, off);

    // post-reduction values are wave-uniform: all lanes compute di
    float wself = expf(1.0f / ((float)nlive + 1.0f));
    float D  = sw_lane + wself;
    float di = rsqrtf(fmaxf(D, 1e-12f));
    if (lane == 0) {
        lend[wid]  = beg + nlive;
        dinv[wid]  = di;
        selfc[wid] = wself * di;   // self term applied to dinv-scaled table
    }
    if (g2 && lane < 40)           // layer-2: hd2 = g2 * di (fp16)
        hd2[(size_t)wid * 40 + lane] = (_Float16)(g2[(size_t)wid * 40 + lane] * di);
}

// dense GEMM out[N,F] = (fea[N,64] @ W[64,F]) * scale[r]; OutT element.
template <int F, typename InT, typename OutT>
__global__ void k_gemm(const InT* __restrict__ fea, const float* __restrict__ W,
                       const float* __restrict__ scale, OutT* __restrict__ out, int n)
{
    constexpr int R = 256 / F;
    __shared__ float sW[64 * F];
    __shared__ float sX[R * 64];
    int tid = threadIdx.x;
    for (int i = tid; i < 64 * F; i += 256) sW[i] = W[i];
    int base = blockIdx.x * R;
    for (int i = tid; i < R * 64; i += 256) {
        int rr = base + i / 64;
        sX[i] = (rr < n) ? (float)fea[(size_t)rr * 64 + (i & 63)] : 0.0f;
    }
    __syncthreads();
    int rl = tid / F, j = tid % F;
    if (rl >= R) return;
    int r = base + rl;
    if (r >= n) return;
    float acc = 0.0f;
#pragma unroll
    for (int k = 0; k < 64; ++k) acc = fmaf(sX[rl * 64 + k], sW[k * F + j], acc);
    out[(size_t)r * F + j] = (OutT)(acc * scale[r]);
}

// transposed live-edge aggregation, generic vec4 element (float4 / half4):
// 4 edges x 16 lanes; lane (eg,q) loads one vec4 of row c_eg at feature q*4.
// Returns per-lane (lane=feature) weighted sum via xor-reduce + transpose.
template <int F, typename Vec4>
__device__ inline float agg_core_t(const Vec4* __restrict__ hdv,
                                   const int2* __restrict__ cw,
                                   int beg, int lend_, int lane)
{
    int q  = lane & 15;
    int eg = lane >> 4;
    bool qact = (F == 64) ? true : (q < (F >> 2));
    float acc0 = 0.f, acc1 = 0.f, acc2 = 0.f, acc3 = 0.f;
    for (int base = beg; base < lend_; base += 64) {
        int idx = base + lane;
        int cv = 0; float wv = 0.0f;
        if (idx < lend_) { int2 pw = cw[idx]; cv = pw.x; wv = __int_as_float(pw.y); }
        int cnt = lend_ - base; if (cnt > 64) cnt = 64;
        for (int j = 0; j < cnt; j += 4) {
            int   c = __shfl(cv, j + eg);   // beyond-cnt lanes hold cv=0,wv=0
            float w = __shfl(wv, j + eg);
            if (qact) {
                Vec4 hv = hdv[(size_t)c * (F >> 2) + q];
                acc0 += w * (float)hv.x;
                acc1 += w * (float)hv.y;
                acc2 += w * (float)hv.z;
                acc3 += w * (float)hv.w;
            }
        }
    }
    acc0 += __shfl_xor(acc0, 16); acc0 += __shfl_xor(acc0, 32);
    acc1 += __shfl_xor(acc1, 16); acc1 += __shfl_xor(acc1, 32);
    acc2 += __shfl_xor(acc2, 16); acc2 += __shfl_xor(acc2, 32);
    acc3 += __shfl_xor(acc3, 16); acc3 += __shfl_xor(acc3, 32);
    int srcq = lane >> 2;
    float a0 = __shfl(acc0, srcq);
    float a1 = __shfl(acc1, srcq);
    float a2 = __shfl(acc2, srcq);
    float a3 = __shfl(acc3, srcq);
    int k = lane & 3;
    return (k == 0) ? a0 : (k == 1) ? a1 : (k == 2) ? a2 : a3;
}

// layer-1 aggregation over fp32 dinv-scaled table + relu; emits fnh (att2)
// and fused g2 = v @ W2 (fp32, unscaled) — replaces the hrelu+gemm40 pass.
__global__ void k_agg64(const float* __restrict__ hd, const int2* __restrict__ cw,
                        const float* __restrict__ dinv, const float* __restrict__ selfc,
                        const float* __restrict__ b, const int* __restrict__ row_ptr,
                        const int* __restrict__ lend, const float* __restrict__ W2,
                        float* __restrict__ g2, float* __restrict__ fnh, int n)
{
    __shared__ float sW2[64 * 40];   // 10 KB
    __shared__ float sv[4][64];
    int tid = threadIdx.x;
    for (int i = tid; i < 64 * 40; i += 256) sW2[i] = W2[i];
    __syncthreads();

    int gid  = blockIdx.x * blockDim.x + tid;
    int wid  = gid >> 6;
    int lane = tid & 63;
    int wib  = tid >> 6;
    if (wid >= n) return;
    int beg = row_ptr[wid], le = lend[wid];
    float accf = agg_core_t<64>((const float4*)hd, cw, beg, le, lane);
    float hs  = hd[(size_t)wid * 64 + lane];  // = h*di
    float v = dinv[wid] * accf + selfc[wid] * hs + b[lane];
    v = fmaxf(v, 0.0f); // relu
    float s = v * v;
#pragma unroll
    for (int off = 32; off > 0; off >>= 1) s += __shfl_xor(s, off);
    float inv = 1.0f / fmaxf(sqrtf(s), 1e-12f);
    fnh[(size_t)wid * 64 + lane] = v * inv;

    // fused v @ W2 (within-wave LDS exchange; no block barrier needed)
    sv[wib][lane] = v;
    if (lane < 40) {
        float acc = 0.0f;
#pragma unroll
        for (int k = 0; k < 64; ++k) acc = fmaf(sv[wib][k], sW2[k * 40 + lane], acc);
        g2[(size_t)wid * 40 + lane] = acc;
    }
}

// layer-2 aggregation (F=40, fp16 table) + bias + log_softmax -> output.
__global__ void k_agg40_lsm(const _Float16* __restrict__ hd2, const int2* __restrict__ cw,
                            const float* __restrict__ dinv, const float* __restrict__ selfc,
                            const float* __restrict__ b, const int* __restrict__ row_ptr,
                            const int* __restrict__ lend,
                            float* __restrict__ out, int n)
{
    constexpr int F = 40;
    int gid  = blockIdx.x * blockDim.x + threadIdx.x;
    int wid  = gid >> 6;
    int lane = threadIdx.x & 63;
    if (wid >= n) return;
    int beg = row_ptr[wid], le = lend[wid];
    float accf = agg_core_t<F>((const half4*)hd2, cw, beg, le, lane);
    bool active = (lane < F);
    float v = 0.0f;
    if (active) {
        float hs = (float)hd2[(size_t)wid * F + lane];
        v = dinv[wid] * accf + selfc[wid] * hs + b[lane];
    }
    float m = active ? v : -__builtin_inff();
#pragma unroll
    for (int off = 32; off > 0; off >>= 1) m = fmaxf(m, __shfl_xor(m, off));
    float ex = active ? expf(v - m) : 0.0f;
    float s = ex;
#pragma unroll
    for (int off = 32; off > 0; off >>= 1) s += __shfl_xor(s, off);
    if (active) out[(size_t)wid * F + lane] = v - m - logf(s);
}

extern "C" void kernel_launch(void* const* d_in, const int* in_sizes, int n_in,
                              void* d_out, int out_size, void* d_ws, size_t ws_size,
                              hipStream_t stream)
{
    const float* x  = (const float*)d_in[0];
    const int*   ei = (const int*)d_in[1];
    const float* W1 = (const float*)d_in[2];
    const float* b1 = (const float*)d_in[3];
    const float* W2 = (const float*)d_in[4];
    const float* b2 = (const float*)d_in[5];
    float* out = (float*)d_out;

    const int N = in_sizes[0] / 64;   // 50000
    const int E = in_sizes[1] / 2;    // 800000
    const int* row = ei;
    const int* col = ei + E;

    const int nblkA = (E + EPB - 1) / EPB;       // edge blocks for bucket sort
    const int nbuck = (N + RPB - 1) / RPB;       // buckets (rows/128)

    char* p = (char*)d_ws;
    auto alloc = [&](size_t bytes) -> char* {
        char* r = p; p += (bytes + 255) & ~(size_t)255; return r;
    };
    float*     fn     = (float*)alloc((size_t)N * 64 * 4);     // normalized x
    float*     dinv   = (float*)alloc((size_t)N * 4);
    float*     selfc  = (float*)alloc((size_t)N * 4);
    float*     hd1    = (float*)alloc((size_t)N * 64 * 4);     // (x@W1)*di (fp32)
    float*     g2     = (float*)alloc((size_t)N * 40 * 4);     // hrelu@W2 (fp32)
    _Float16*  hd2    = (_Float16*)alloc((size_t)N * 40 * 2);  // g2*di2 (fp16)
    float*     fnh    = (float*)alloc((size_t)N * 64 * 4);     // normalized hrelu
    int*       rptr   = (int*)alloc((size_t)(N + 1) * 4);
    int*       lendv  = (int*)alloc((size_t)N * 4);
    int*       col_s  = (int*)alloc((size_t)E * 4);
    int2*      cw     = (int2*)alloc((size_t)E * 8);           // packed (col,w)
    int*       ebuf   = (int*)alloc((size_t)nbuck * CAPB * 4); // slack-segmented
    int*       gcur   = (int*)alloc((size_t)nbuck * 4);

    const int TB = 256;
    int blk_nodeWave = (N * 64 + TB - 1) / TB;   // 12500
    int blk_node4    = (N + 3) / 4;              // 12500

    hipMemsetAsync(gcur, 0, (size_t)nbuck * 4, stream);

    // ---- CSR build + x normalization (fused)
    k_bscat_norm<<<nblkA + blk_nodeWave, TB, 0, stream>>>(row, col, gcur, ebuf,
                                                          E, nbuck, nblkA, x, fn, N);
    k_csr<<<nbuck, TB, 0, stream>>>(ebuf, gcur, rptr, col_s, N, E, nbuck);

    // ---- layer 1
    k_att<<<blk_node4, TB, 0, stream>>>(fn, rptr, col_s, cw, lendv, dinv, selfc,
                                        (const float*)nullptr, (_Float16*)nullptr, N);
    k_gemm<64, float, float><<<(N + 3) / 4, TB, 0, stream>>>(x, W1, dinv, hd1, N);
    k_agg64<<<blk_nodeWave, TB, 0, stream>>>(hd1, cw, dinv, selfc, b1,
                                             rptr, lendv, W2, g2, fnh, N);

    // ---- layer 2 (att epilogue scales g2 -> hd2; agg40 finishes)
    k_att<<<blk_node4, TB, 0, stream>>>(fnh, rptr, col_s, cw, lendv, dinv, selfc,
                                        g2, hd2, N);
    k_agg40_lsm<<<blk_nodeWave, TB, 0, stream>>>(hd2, cw, dinv, selfc, b2,
                                                 rptr, lendv, out, N);
}

// Round 14
// 258.121 us; speedup vs baseline: 1.1111x; 1.0163x over previous
//
#include <hip/hip_runtime.h>
#include <math.h>

// ---------------------------------------------------------------------------
// GuardNet: 2-layer attention-weighted GCN.
// R14: k_agg64 processes 16 nodes/block (4/wave loop) — amortizes the 10KB
// W2 LDS staging 16x (was 512MB of L2->LDS traffic across 12500 blocks,
// ~15us of pure W2 re-read; now 32MB). Rest = R13.
// ---------------------------------------------------------------------------

#define ATT_CAP 96      // per-node LDS sim stash; deg>CAP falls back to recompute
#define EPB     2048    // edges per bucket-sort block (= 8 per thread at TB=256)
#define RPB     128     // rows per bucket (bucket = row>>7)
#define NBUCK_MAX 512
#define CAPB    4096    // slack per bucket (mean 2048, sigma~45 -> never hit)

typedef _Float16 half4 __attribute__((ext_vector_type(4)));

// fused: blocks [0,nblkA) = bucket scatter; blocks [nblkA,..) = fn row norm.
__global__ void k_bscat_norm(const int* __restrict__ row, const int* __restrict__ col,
                             int* __restrict__ gcur, int* __restrict__ ebuf,
                             int E, int nbuck, int nblkA,
                             const float* __restrict__ x, float* __restrict__ fn, int N)
{
    __shared__ int lh[NBUCK_MAX];
    __shared__ int lbase[NBUCK_MAX];
    if ((int)blockIdx.x >= nblkA) {
        // ---- normfn body
        int gid  = (blockIdx.x - nblkA) * blockDim.x + threadIdx.x;
        int wid  = gid >> 6;
        int lane = threadIdx.x & 63;
        if (wid >= N) return;
        float v = x[(size_t)wid * 64 + lane];
        float s = v * v;
#pragma unroll
        for (int off = 32; off > 0; off >>= 1) s += __shfl_xor(s, off);
        float inv = 1.0f / fmaxf(sqrtf(s), 1e-12f);
        fn[(size_t)wid * 64 + lane] = v * inv;
        return;
    }
    // ---- bucket scatter body
    int b = blockIdx.x;
    int ebeg = b * EPB;
    int rr[8], cc[8];
    for (int i = threadIdx.x; i < nbuck; i += blockDim.x) lh[i] = 0;
    __syncthreads();
#pragma unroll
    for (int k = 0; k < 8; ++k) {
        int e = ebeg + k * 256 + threadIdx.x;
        bool v = (e < E);
        int r = v ? row[e] : -1;
        int c = v ? col[e] : 0;
        rr[k] = r; cc[k] = c;
        if (v) atomicAdd(&lh[r >> 7], 1);
    }
    __syncthreads();
    for (int i = threadIdx.x; i < nbuck; i += blockDim.x) {
        int cnt = lh[i];
        if (cnt) lbase[i] = i * CAPB + atomicAdd(gcur + i, cnt);
        lh[i] = 0;                       // reuse as local cursor
    }
    __syncthreads();
#pragma unroll
    for (int k = 0; k < 8; ++k) {
        int r = rr[k];
        if (r >= 0) {
            int j = r >> 7;
            int pos = lbase[j] + atomicAdd(&lh[j], 1);
            ebuf[pos] = ((r & (RPB - 1)) << 16) | cc[k];
        }
    }
}

// one block per bucket: computes own exclusive prefix of gcur, LDS row-binning
// of its slack segment, coalesced col_s + rptr writes.
__global__ void k_csr(const int* __restrict__ ebuf, const int* __restrict__ gcur,
                      int* __restrict__ rptr, int* __restrict__ col_s,
                      int N, int E, int nbuck)
{
    __shared__ int pk[CAPB];
    __shared__ int lcol[CAPB];
    __shared__ int lcnt[RPB], lexc[RPB], lcur[RPB];
    __shared__ int spart[4];
    int j = blockIdx.x;
    int tid = threadIdx.x;
    int lane = tid & 63, wave = tid >> 6;

    // exclusive prefix: beg = sum(gcur[0..j))
    int part = 0;
    for (int i = tid; i < j; i += blockDim.x) part += gcur[i];
#pragma unroll
    for (int off = 32; off > 0; off >>= 1) part += __shfl_xor(part, off);
    if (lane == 0) spart[wave] = part;
    if (tid < RPB) lcnt[tid] = 0;
    __syncthreads();
    int beg = spart[0] + spart[1] + spart[2] + spart[3];
    int m = gcur[j]; if (m > CAPB) m = CAPB;     // never hit

    const int* seg = ebuf + (size_t)j * CAPB;
    for (int i = tid; i < m; i += blockDim.x) pk[i] = seg[i];
    __syncthreads();
    for (int i = tid; i < m; i += blockDim.x) atomicAdd(&lcnt[pk[i] >> 16], 1);
    __syncthreads();
    if (tid < 64) {                    // wave 0 scans 128 counts (2 per lane)
        int a = lcnt[2 * tid], b2 = lcnt[2 * tid + 1];
        int s = a + b2;
        int incl = s;
#pragma unroll
        for (int off = 1; off < 64; off <<= 1) {
            int v = __shfl_up(incl, off);
            if (tid >= off) incl += v;
        }
        int base = incl - s;
        lexc[2 * tid] = base;     lexc[2 * tid + 1] = base + a;
        lcur[2 * tid] = base;     lcur[2 * tid + 1] = base + a;
    }
    __syncthreads();
    for (int i = tid; i < m; i += blockDim.x) {
        int v = pk[i];
        int p = atomicAdd(&lcur[v >> 16], 1);
        lcol[p] = v & 0xFFFF;
    }
    __syncthreads();
    for (int i = tid; i < m; i += blockDim.x) col_s[beg + i] = lcol[i];
    if (tid < RPB) {
        int r = j * RPB + tid;
        if (r < N) rptr[r] = beg + lexc[tid];
    }
    if (j == 0 && tid == 0) rptr[N] = E;
}

// fused attention: per node (wave): pass1 = edge cosine sims (4 lanes/edge,
// 16 edges/iter) stashed in LDS + wave-reduced row-sum; pass2 = w=exp(sim/rs),
// ballot-rank compaction into packed cw=(col,w), lend/dinv/selfc. No atomics.
// Optional layer-2 epilogue: hd2[wid] = g2[wid] * di (di wave-uniform).
__global__ void k_att(const float* __restrict__ fn,
                      const int* __restrict__ rptr, const int* __restrict__ col_s,
                      int2* __restrict__ cw, int* __restrict__ lend,
                      float* __restrict__ dinv, float* __restrict__ selfc,
                      const float* __restrict__ g2, _Float16* __restrict__ hd2, int n)
{
    __shared__ float ssim[4][ATT_CAP];
    __shared__ int   scol[4][ATT_CAP];
    int wib  = threadIdx.x >> 6;
    int wid  = blockIdx.x * 4 + wib;
    int lane = threadIdx.x & 63;
    if (wid >= n) return;
    int sub = lane & 3;       // lane within 4-lane edge group
    int grp = lane >> 2;      // edge group 0..15
    int beg = rptr[wid], end = rptr[wid + 1];
    int deg_all = end - beg;

    const float4* frp = (const float4*)(fn + (size_t)wid * 64);
    float4 a0 = frp[sub], a1 = frp[sub + 4], a2 = frp[sub + 8], a3 = frp[sub + 12];

    // pass 1: sims + row-sum (16 edges per iteration)
    float rs_part = 0.0f;
    int ngrp = (deg_all + 15) >> 4;
    for (int g = 0; g < ngrp; ++g) {
        int li = g * 16 + grp;
        float s = 0.0f; int c = 0;
        bool valid = (li < deg_all);
        if (valid) {
            c = col_s[beg + li];
            const float4* fcp = (const float4*)(fn + (size_t)c * 64);
            float4 b0 = fcp[sub], b1 = fcp[sub + 4], b2 = fcp[sub + 8], b3 = fcp[sub + 12];
            float p = a0.x * b0.x + a0.y * b0.y + a0.z * b0.z + a0.w * b0.w
                    + a1.x * b1.x + a1.y * b1.y + a1.z * b1.z + a1.w * b1.w
                    + a2.x * b2.x + a2.y * b2.y + a2.z * b2.z + a2.w * b2.w
                    + a3.x * b3.x + a3.y * b3.y + a3.z * b3.z + a3.w * b3.w;
            p += __shfl_xor(p, 1);
            p += __shfl_xor(p, 2);
            s = (p < 0.1f) ? 0.0f : p;
        }
        if (sub == 0 && valid) {
            if (li < ATT_CAP) { ssim[wib][li] = s; scol[wib][li] = c; }
            if (s > 0.0f) rs_part += s;
        }
    }
#pragma unroll
    for (int off = 32; off > 0; off >>= 1) rs_part += __shfl_xor(rs_part, off);
    float denom = fmaxf(rs_part, 1e-12f);

    // pass 2: weights + live compaction (lane = edge index within 64-chunk)
    int   nlive = 0;
    float sw_lane = 0.0f;
    for (int base = 0; base < deg_all; base += 64) {
        int li = base + lane;
        bool valid = (li < deg_all);
        float s = 0.0f; int c = 0;
        if (valid) {
            if (li < ATT_CAP) { s = ssim[wib][li]; c = scol[wib][li]; }
            else {                           // astronomically rare: per-lane dot
                c = col_s[beg + li];
                const float* fr = fn + (size_t)wid * 64;
                const float* fc = fn + (size_t)c * 64;
                float p = 0.0f;
                for (int k = 0; k < 64; ++k) p += fr[k] * fc[k];
                s = (p < 0.1f) ? 0.0f : p;
            }
        }
        float w = (valid && s > 0.0f) ? expf(s / denom) : 0.0f;
        unsigned long long M = __ballot(w > 0.0f);
        int rank = __popcll(M & ((1ull << lane) - 1ull));
        if (w > 0.0f) {
            int2 pw; pw.x = c; pw.y = __float_as_int(w);
            cw[beg + nlive + rank] = pw;
            sw_lane += w;
        }
        nlive += __popcll(M);
    }
#pragma unroll
    for (int off = 32; off > 0; off >>= 1) sw_lane += __shfl_xor(sw_lane, off);

    // post-reduction values are wave-uniform: all lanes compute di
    float wself = expf(1.0f / ((float)nlive + 1.0f));
    float D  = sw_lane + wself;
    float di = rsqrtf(fmaxf(D, 1e-12f));
    if (lane == 0) {
        lend[wid]  = beg + nlive;
        dinv[wid]  = di;
        selfc[wid] = wself * di;   // self term applied to dinv-scaled table
    }
    if (g2 && lane < 40)           // layer-2: hd2 = g2 * di (fp16)
        hd2[(size_t)wid * 40 + lane] = (_Float16)(g2[(size_t)wid * 40 + lane] * di);
}

// dense GEMM out[N,F] = (fea[N,64] @ W[64,F]) * scale[r]; OutT element.
template <int F, typename InT, typename OutT>
__global__ void k_gemm(const InT* __restrict__ fea, const float* __restrict__ W,
                       const float* __restrict__ scale, OutT* __restrict__ out, int n)
{
    constexpr int R = 256 / F;
    __shared__ float sW[64 * F];
    __shared__ float sX[R * 64];
    int tid = threadIdx.x;
    for (int i = tid; i < 64 * F; i += 256) sW[i] = W[i];
    int base = blockIdx.x * R;
    for (int i = tid; i < R * 64; i += 256) {
        int rr = base + i / 64;
        sX[i] = (rr < n) ? (float)fea[(size_t)rr * 64 + (i & 63)] : 0.0f;
    }
    __syncthreads();
    int rl = tid / F, j = tid % F;
    if (rl >= R) return;
    int r = base + rl;
    if (r >= n) return;
    float acc = 0.0f;
#pragma unroll
    for (int k = 0; k < 64; ++k) acc = fmaf(sX[rl * 64 + k], sW[k * F + j], acc);
    out[(size_t)r * F + j] = (OutT)(acc * scale[r]);
}

// transposed live-edge aggregation, generic vec4 element (float4 / half4):
// 4 edges x 16 lanes; lane (eg,q) loads one vec4 of row c_eg at feature q*4.
// Returns per-lane (lane=feature) weighted sum via xor-reduce + transpose.
template <int F, typename Vec4>
__device__ inline float agg_core_t(const Vec4* __restrict__ hdv,
                                   const int2* __restrict__ cw,
                                   int beg, int lend_, int lane)
{
    int q  = lane & 15;
    int eg = lane >> 4;
    bool qact = (F == 64) ? true : (q < (F >> 2));
    float acc0 = 0.f, acc1 = 0.f, acc2 = 0.f, acc3 = 0.f;
    for (int base = beg; base < lend_; base += 64) {
        int idx = base + lane;
        int cv = 0; float wv = 0.0f;
        if (idx < lend_) { int2 pw = cw[idx]; cv = pw.x; wv = __int_as_float(pw.y); }
        int cnt = lend_ - base; if (cnt > 64) cnt = 64;
        for (int j = 0; j < cnt; j += 4) {
            int   c = __shfl(cv, j + eg);   // beyond-cnt lanes hold cv=0,wv=0
            float w = __shfl(wv, j + eg);
            if (qact) {
                Vec4 hv = hdv[(size_t)c * (F >> 2) + q];
                acc0 += w * (float)hv.x;
                acc1 += w * (float)hv.y;
                acc2 += w * (float)hv.z;
                acc3 += w * (float)hv.w;
            }
        }
    }
    acc0 += __shfl_xor(acc0, 16); acc0 += __shfl_xor(acc0, 32);
    acc1 += __shfl_xor(acc1, 16); acc1 += __shfl_xor(acc1, 32);
    acc2 += __shfl_xor(acc2, 16); acc2 += __shfl_xor(acc2, 32);
    acc3 += __shfl_xor(acc3, 16); acc3 += __shfl_xor(acc3, 32);
    int srcq = lane >> 2;
    float a0 = __shfl(acc0, srcq);
    float a1 = __shfl(acc1, srcq);
    float a2 = __shfl(acc2, srcq);
    float a3 = __shfl(acc3, srcq);
    int k = lane & 3;
    return (k == 0) ? a0 : (k == 1) ? a1 : (k == 2) ? a2 : a3;
}

// layer-1 aggregation over fp32 dinv-scaled table + relu; emits fnh (att2)
// and fused g2 = v @ W2. 16 nodes/block (4 per wave) to amortize W2 staging.
__global__ void k_agg64(const float* __restrict__ hd, const int2* __restrict__ cw,
                        const float* __restrict__ dinv, const float* __restrict__ selfc,
                        const float* __restrict__ b, const int* __restrict__ row_ptr,
                        const int* __restrict__ lend, const float* __restrict__ W2,
                        float* __restrict__ g2, float* __restrict__ fnh, int n)
{
    __shared__ float sW2[64 * 40];   // 10 KB, staged once per block (16 nodes)
    __shared__ float sv[4][64];
    int tid = threadIdx.x;
    for (int i = tid; i < 64 * 40; i += 256) sW2[i] = W2[i];
    __syncthreads();

    int lane = tid & 63;
    int wib  = tid >> 6;
    for (int t = 0; t < 4; ++t) {
        int wid = blockIdx.x * 16 + wib * 4 + t;
        if (wid >= n) break;
        int beg = row_ptr[wid], le = lend[wid];
        float accf = agg_core_t<64>((const float4*)hd, cw, beg, le, lane);
        float hs  = hd[(size_t)wid * 64 + lane];  // = h*di
        float v = dinv[wid] * accf + selfc[wid] * hs + b[lane];
        v = fmaxf(v, 0.0f); // relu
        float s = v * v;
#pragma unroll
        for (int off = 32; off > 0; off >>= 1) s += __shfl_xor(s, off);
        float inv = 1.0f / fmaxf(sqrtf(s), 1e-12f);
        fnh[(size_t)wid * 64 + lane] = v * inv;

        // fused v @ W2 (within-wave LDS exchange; no block barrier needed)
        sv[wib][lane] = v;
        if (lane < 40) {
            float acc = 0.0f;
#pragma unroll
            for (int k = 0; k < 64; ++k) acc = fmaf(sv[wib][k], sW2[k * 40 + lane], acc);
            g2[(size_t)wid * 40 + lane] = acc;
        }
    }
}

// layer-2 aggregation (F=40, fp16 table) + bias + log_softmax -> output.
__global__ void k_agg40_lsm(const _Float16* __restrict__ hd2, const int2* __restrict__ cw,
                            const float* __restrict__ dinv, const float* __restrict__ selfc,
                            const float* __restrict__ b, const int* __restrict__ row_ptr,
                            const int* __restrict__ lend,
                            float* __restrict__ out, int n)
{
    constexpr int F = 40;
    int gid  = blockIdx.x * blockDim.x + threadIdx.x;
    int wid  = gid >> 6;
    int lane = threadIdx.x & 63;
    if (wid >= n) return;
    int beg = row_ptr[wid], le = lend[wid];
    float accf = agg_core_t<F>((const half4*)hd2, cw, beg, le, lane);
    bool active = (lane < F);
    float v = 0.0f;
    if (active) {
        float hs = (float)hd2[(size_t)wid * F + lane];
        v = dinv[wid] * accf + selfc[wid] * hs + b[lane];
    }
    float m = active ? v : -__builtin_inff();
#pragma unroll
    for (int off = 32; off > 0; off >>= 1) m = fmaxf(m, __shfl_xor(m, off));
    float ex = active ? expf(v - m) : 0.0f;
    float s = ex;
#pragma unroll
    for (int off = 32; off > 0; off >>= 1) s += __shfl_xor(s, off);
    if (active) out[(size_t)wid * F + lane] = v - m - logf(s);
}

extern "C" void kernel_launch(void* const* d_in, const int* in_sizes, int n_in,
                              void* d_out, int out_size, void* d_ws, size_t ws_size,
                              hipStream_t stream)
{
    const float* x  = (const float*)d_in[0];
    const int*   ei = (const int*)d_in[1];
    const float* W1 = (const float*)d_in[2];
    const float* b1 = (const float*)d_in[3];
    const float* W2 = (const float*)d_in[4];
    const float* b2 = (const float*)d_in[5];
    float* out = (float*)d_out;

    const int N = in_sizes[0] / 64;   // 50000
    const int E = in_sizes[1] / 2;    // 800000
    const int* row = ei;
    const int* col = ei + E;

    const int nblkA = (E + EPB - 1) / EPB;       // edge blocks for bucket sort
    const int nbuck = (N + RPB - 1) / RPB;       // buckets (rows/128)

    char* p = (char*)d_ws;
    auto alloc = [&](size_t bytes) -> char* {
        char* r = p; p += (bytes + 255) & ~(size_t)255; return r;
    };
    float*     fn     = (float*)alloc((size_t)N * 64 * 4);     // normalized x
    float*     dinv   = (float*)alloc((size_t)N * 4);
    float*     selfc  = (float*)alloc((size_t)N * 4);
    float*     hd1    = (float*)alloc((size_t)N * 64 * 4);     // (x@W1)*di (fp32)
    float*     g2     = (float*)alloc((size_t)N * 40 * 4);     // hrelu@W2 (fp32)
    _Float16*  hd2    = (_Float16*)alloc((size_t)N * 40 * 2);  // g2*di2 (fp16)
    float*     fnh    = (float*)alloc((size_t)N * 64 * 4);     // normalized hrelu
    int*       rptr   = (int*)alloc((size_t)(N + 1) * 4);
    int*       lendv  = (int*)alloc((size_t)N * 4);
    int*       col_s  = (int*)alloc((size_t)E * 4);
    int2*      cw     = (int2*)alloc((size_t)E * 8);           // packed (col,w)
    int*       ebuf   = (int*)alloc((size_t)nbuck * CAPB * 4); // slack-segmented
    int*       gcur   = (int*)alloc((size_t)nbuck * 4);

    const int TB = 256;
    int blk_nodeWave = (N * 64 + TB - 1) / TB;   // 12500
    int blk_node4    = (N + 3) / 4;              // 12500
    int blk_node16   = (N + 15) / 16;            // 3125

    hipMemsetAsync(gcur, 0, (size_t)nbuck * 4, stream);

    // ---- CSR build + x normalization (fused)
    k_bscat_norm<<<nblkA + blk_nodeWave, TB, 0, stream>>>(row, col, gcur, ebuf,
                                                          E, nbuck, nblkA, x, fn, N);
    k_csr<<<nbuck, TB, 0, stream>>>(ebuf, gcur, rptr, col_s, N, E, nbuck);

    // ---- layer 1
    k_att<<<blk_node4, TB, 0, stream>>>(fn, rptr, col_s, cw, lendv, dinv, selfc,
                                        (const float*)nullptr, (_Float16*)nullptr, N);
    k_gemm<64, float, float><<<(N + 3) / 4, TB, 0, stream>>>(x, W1, dinv, hd1, N);
    k_agg64<<<blk_node16, TB, 0, stream>>>(hd1, cw, dinv, selfc, b1,
                                           rptr, lendv, W2, g2, fnh, N);

    // ---- layer 2 (att epilogue scales g2 -> hd2; agg40 finishes)
    k_att<<<blk_node4, TB, 0, stream>>>(fnh, rptr, col_s, cw, lendv, dinv, selfc,
                                        g2, hd2, N);
    k_agg40_lsm<<<blk_nodeWave, TB, 0, stream>>>(hd2, cw, dinv, selfc, b2,
                                                 rptr, lendv, out, N);
}